// Round 2
// baseline (1391.543 us; speedup 1.0000x reference)
//
#include <hip/hip_runtime.h>
#include <math.h>

#define B 32
#define S 4096
#define N 1024

typedef short short8 __attribute__((ext_vector_type(8)));
typedef short short4v __attribute__((ext_vector_type(4)));
typedef float float4v __attribute__((ext_vector_type(4)));

__device__ inline short f2bf(float f) {
    unsigned u = __builtin_bit_cast(unsigned, f);
    u += 0x7fffu + ((u >> 16) & 1u);   // RNE
    return (short)(u >> 16);
}

// async global->LDS DMA, 16 B per lane. LDS dest must be wave-uniform;
// HW writes lds_base + lane*16 (linear). Source addr is per-lane.
__device__ __forceinline__ void load_lds16(const void* g, void* l) {
    __builtin_amdgcn_global_load_lds(
        (const __attribute__((address_space(1))) void*)g,
        (__attribute__((address_space(3))) void*)l, 16, 0, 0);
}

// ---------------------------------------------------------------------------
// Kernel 1: dec_feats[b][m] = dot(dec_in_state[b], Ws[m]) + bs[m]  (fp32, tiny)
// ---------------------------------------------------------------------------
__global__ __launch_bounds__(256)
void dec_feats_kernel(const float* __restrict__ dec, const float* __restrict__ Ws,
                      const float* __restrict__ bs, float* __restrict__ dec_feats) {
    int t = blockIdx.x * blockDim.x + threadIdx.x; // 0 .. B*N-1
    int b = t & (B - 1);
    int m = t >> 5;
    const float4* drow = (const float4*)(dec + (size_t)b * N);
    const float4* wrow = (const float4*)(Ws + (size_t)m * N);
    float acc = 0.f;
    for (int n4 = 0; n4 < N / 4; ++n4) {
        float4 a = drow[n4];
        float4 w = wrow[n4];
        acc += a.x * w.x + a.y * w.y + a.z * w.z + a.w * w.w;
    }
    dec_feats[(size_t)b * N + m] = acc + bs[m];
}

// ---------------------------------------------------------------------------
// Kernel 1b: fp32 -> bf16 one-time conversion (memory-bound, grid-stride).
// 8 elems/thread: 32 B read, 16 B write per iteration. Eliminates the 2.1G
// redundant per-block f2bf conversions the old staging path paid.
// ---------------------------------------------------------------------------
__global__ __launch_bounds__(256)
void cvt_bf16_kernel(const float* __restrict__ src, short* __restrict__ dst,
                     size_t n8) {
    size_t i = (size_t)blockIdx.x * 256 + threadIdx.x;
    size_t stride = (size_t)gridDim.x * 256;
    for (; i < n8; i += stride) {
        const float4v* s = (const float4v*)(src + i * 8);
        float4v a = s[0], b = s[1];
        short8 o = { f2bf(a.x), f2bf(a.y), f2bf(a.z), f2bf(a.w),
                     f2bf(b.x), f2bf(b.y), f2bf(b.z), f2bf(b.w) };
        *(short8*)(dst + i * 8) = o;
    }
}

#define BR 128
#define BM 128
#define BK 64

// ---------------------------------------------------------------------------
// Kernel 2a (fast path): m97-structure bf16 MFMA GEMM with fused tanh·v epilogue.
// e[r] += sum_m tanh( enc[r]·Wh[m] + bh[m] + dec_feats[b][m] + cov[r]*wc[m] ) * v[m]
// 128x128 tile, BK=64, 4 waves each owning a 64x64 quadrant (4x4 of 16x16x32).
// Staging via global_load_lds width-16 into LINEAR [128][64] LDS (no pad:
// required by global_load_lds; T2 swizzle is null on 2-phase 128^2 per guide).
// ---------------------------------------------------------------------------
__global__ __launch_bounds__(256)
void score_mfma_bf16_kernel(const short* __restrict__ encb, const short* __restrict__ Whb,
                            const float* __restrict__ bh, const float* __restrict__ dec_feats,
                            const float* __restrict__ cov, const float* __restrict__ wc,
                            const float* __restrict__ v, float* __restrict__ e) {
    __shared__ short As[BR][BK];
    __shared__ short Bs[BM][BK];

    // XCD swizzle: the 8 m-tiles of one row-tile share h&7 -> same XCD ->
    // enc rows fetched once per XCD L2.
    unsigned h   = blockIdx.x;
    unsigned xcd = h & 7u;
    unsigned mt  = (h >> 3) & 7u;
    unsigned g   = h >> 6;
    int r0 = (int)(xcd + 8u * g) * BR;   // row tile 0..1023
    int m0 = (int)mt * BM;

    int t    = threadIdx.x;
    int lane = t & 63;
    int w    = t >> 6;
    int wr   = (w >> 1) * 64;
    int wm   = (w & 1) * 64;
    int cq   = lane >> 4;   // 0..3
    int cm   = lane & 15;

    float4v acc[4][4];
#pragma unroll
    for (int i = 0; i < 4; ++i)
#pragma unroll
        for (int j = 0; j < 4; ++j) acc[i][j] = (float4v){0.f, 0.f, 0.f, 0.f};

    // One wave-load = 64 lanes x 16 B = 8 rows x 64 bf16 cols, LDS-linear.
    // lane l -> row l>>3, col (l&7)*8; LDS offset l*16 B matches exactly.
    int lrow = lane >> 3;
    int lcol = (lane & 7) * 8;
    const short* aR = encb + (size_t)(r0 + w * 32 + lrow) * N + lcol;
    const short* bR = Whb  + (size_t)(m0 + w * 32 + lrow) * N + lcol;

    for (int k0 = 0; k0 < N; k0 += BK) {
#pragma unroll
        for (int i = 0; i < 4; ++i) {
            load_lds16(aR + (size_t)(i * 8) * N + k0, &As[w * 32 + i * 8][0]);
            load_lds16(bR + (size_t)(i * 8) * N + k0, &Bs[w * 32 + i * 8][0]);
        }
        __syncthreads();   // compiler emits vmcnt(0) drain before s_barrier
#pragma unroll
        for (int ks = 0; ks < BK; ks += 32) {
            short8 af[4], bfr[4];
#pragma unroll
            for (int i = 0; i < 4; ++i)
                af[i] = *(const short8*)&As[wr + i * 16 + cm][ks + cq * 8];
#pragma unroll
            for (int j = 0; j < 4; ++j)
                bfr[j] = *(const short8*)&Bs[wm + j * 16 + cm][ks + cq * 8];
#pragma unroll
            for (int i = 0; i < 4; ++i)
#pragma unroll
                for (int j = 0; j < 4; ++j)
                    acc[i][j] = __builtin_amdgcn_mfma_f32_16x16x32_bf16(
                        af[i], bfr[j], acc[i][j], 0, 0, 0);
        }
        __syncthreads();
    }

    // Epilogue. C/D layout (verified m89/m91): col = lane&15, row = (lane>>4)*4 + reg.
    int b = r0 >> 12;                       // r0 / S; tiles never straddle batches
    const float* df = dec_feats + ((size_t)b << 10);

    float basej[4], wcj[4], vj[4];
#pragma unroll
    for (int j = 0; j < 4; ++j) {
        int m = m0 + wm + j * 16 + cm;
        basej[j] = bh[m] + df[m];
        wcj[j]   = wc[m];
        vj[j]    = v[m];
    }

#pragma unroll
    for (int i = 0; i < 4; ++i) {
        int rbase = r0 + wr + i * 16 + cq * 4;
        float cv[4];
#pragma unroll
        for (int reg = 0; reg < 4; ++reg) cv[reg] = cov[rbase + reg];
        float rs[4] = {0.f, 0.f, 0.f, 0.f};
#pragma unroll
        for (int j = 0; j < 4; ++j) {
#pragma unroll
            for (int reg = 0; reg < 4; ++reg) {
                float val = acc[i][j][reg] + basej[j] + cv[reg] * wcj[j];
                val = fminf(fmaxf(val, -30.f), 30.f);     // keep exp finite
                float texp = __expf(2.f * val);
                float th = (texp - 1.f) * __builtin_amdgcn_rcpf(texp + 1.f);
                rs[reg] += th * vj[j];
            }
        }
#pragma unroll
        for (int reg = 0; reg < 4; ++reg) {
            float p = rs[reg];
            p += __shfl_xor(p, 1);
            p += __shfl_xor(p, 2);
            p += __shfl_xor(p, 4);
            p += __shfl_xor(p, 8);
            if (cm == 0) atomicAdd(&e[rbase + reg], p);
        }
    }
}

// ---------------------------------------------------------------------------
// Kernel 2b (fallback if workspace too small for bf16 copies): previous
// verified fp32-staging MFMA kernel, unchanged.
// ---------------------------------------------------------------------------
#define LDK (BK + 8)   // 72 shorts: 2-way LDS aliasing only (free)

__global__ __launch_bounds__(256)
void score_mfma_kernel(const float* __restrict__ enc, const float* __restrict__ Wh,
                       const float* __restrict__ bh, const float* __restrict__ dec_feats,
                       const float* __restrict__ cov, const float* __restrict__ wc,
                       const float* __restrict__ v, float* __restrict__ e) {
    __shared__ short As[BR][LDK];
    __shared__ short Bs[BM][LDK];

    unsigned h   = blockIdx.x;
    unsigned xcd = h & 7u;
    unsigned mt  = (h >> 3) & 7u;
    unsigned g   = h >> 6;
    int r0 = (int)(xcd + 8u * g) * BR;
    int m0 = (int)mt * BM;

    int t    = threadIdx.x;
    int lane = t & 63;
    int w    = t >> 6;
    int wr   = (w >> 1) * 64;
    int wm   = (w & 1) * 64;
    int cq   = lane >> 4;
    int cm   = lane & 15;

    float4v acc[4][4];
#pragma unroll
    for (int i = 0; i < 4; ++i)
#pragma unroll
        for (int j = 0; j < 4; ++j) acc[i][j] = (float4v){0.f, 0.f, 0.f, 0.f};

    int srow = t >> 4;
    int scol = (t & 15) * 4;

    for (int k0 = 0; k0 < N; k0 += BK) {
#pragma unroll
        for (int p = 0; p < 8; ++p) {
            int row = p * 16 + srow;
            float4v a = *(const float4v*)(enc + (size_t)(r0 + row) * N + k0 + scol);
            short4v ap = { f2bf(a.x), f2bf(a.y), f2bf(a.z), f2bf(a.w) };
            *(short4v*)&As[row][scol] = ap;
            float4v bq = *(const float4v*)(Wh + (size_t)(m0 + row) * N + k0 + scol);
            short4v bp = { f2bf(bq.x), f2bf(bq.y), f2bf(bq.z), f2bf(bq.w) };
            *(short4v*)&Bs[row][scol] = bp;
        }
        __syncthreads();
#pragma unroll
        for (int ks = 0; ks < BK; ks += 32) {
            short8 af[4], bfr[4];
#pragma unroll
            for (int i = 0; i < 4; ++i)
                af[i] = *(const short8*)&As[wr + i * 16 + cm][ks + cq * 8];
#pragma unroll
            for (int j = 0; j < 4; ++j)
                bfr[j] = *(const short8*)&Bs[wm + j * 16 + cm][ks + cq * 8];
#pragma unroll
            for (int i = 0; i < 4; ++i)
#pragma unroll
                for (int j = 0; j < 4; ++j)
                    acc[i][j] = __builtin_amdgcn_mfma_f32_16x16x32_bf16(
                        af[i], bfr[j], acc[i][j], 0, 0, 0);
        }
        __syncthreads();
    }

    int b = r0 >> 12;
    const float* df = dec_feats + ((size_t)b << 10);

    float basej[4], wcj[4], vj[4];
#pragma unroll
    for (int j = 0; j < 4; ++j) {
        int m = m0 + wm + j * 16 + cm;
        basej[j] = bh[m] + df[m];
        wcj[j]   = wc[m];
        vj[j]    = v[m];
    }

#pragma unroll
    for (int i = 0; i < 4; ++i) {
        int rbase = r0 + wr + i * 16 + cq * 4;
        float cv[4];
#pragma unroll
        for (int reg = 0; reg < 4; ++reg) cv[reg] = cov[rbase + reg];
        float rs[4] = {0.f, 0.f, 0.f, 0.f};
#pragma unroll
        for (int j = 0; j < 4; ++j) {
#pragma unroll
            for (int reg = 0; reg < 4; ++reg) {
                float val = acc[i][j][reg] + basej[j] + cv[reg] * wcj[j];
                val = fminf(fmaxf(val, -30.f), 30.f);
                float texp = __expf(2.f * val);
                float th = (texp - 1.f) * __builtin_amdgcn_rcpf(texp + 1.f);
                rs[reg] += th * vj[j];
            }
        }
#pragma unroll
        for (int reg = 0; reg < 4; ++reg) {
            float p = rs[reg];
            p += __shfl_xor(p, 1);
            p += __shfl_xor(p, 2);
            p += __shfl_xor(p, 4);
            p += __shfl_xor(p, 8);
            if (cm == 0) atomicAdd(&e[rbase + reg], p);
        }
    }
}

// ---------------------------------------------------------------------------
// Kernel 3: masked softmax (renormalized masked softmax == plain masked
// softmax algebraically) + coverage update. One block per batch row.
// ---------------------------------------------------------------------------
__global__ __launch_bounds__(256)
void softmax_kernel(const float* __restrict__ e, const int* __restrict__ lens,
                    const float* __restrict__ cov,
                    float* __restrict__ attn, float* __restrict__ cov_out) {
    int b = blockIdx.x;
    int len = lens[b];
    const float* eb = e + (size_t)b * S;
    __shared__ float red[256];
    int t = threadIdx.x;

    float mx = -INFINITY;
    for (int s = t; s < S; s += 256)
        if (s < len) mx = fmaxf(mx, eb[s]);
    red[t] = mx; __syncthreads();
    for (int off = 128; off > 0; off >>= 1) {
        if (t < off) red[t] = fmaxf(red[t], red[t + off]);
        __syncthreads();
    }
    mx = red[0]; __syncthreads();

    float sum = 0.f;
    for (int s = t; s < S; s += 256)
        if (s < len) sum += __expf(eb[s] - mx);
    red[t] = sum; __syncthreads();
    for (int off = 128; off > 0; off >>= 1) {
        if (t < off) red[t] += red[t + off];
        __syncthreads();
    }
    float inv = 1.f / red[0];

    for (int s = t; s < S; s += 256) {
        float a = (s < len) ? __expf(eb[s] - mx) * inv : 0.f;
        attn[(size_t)b * S + s] = a;
        cov_out[(size_t)b * S + s] = cov[(size_t)b * S + s] + a;
    }
}

// ---------------------------------------------------------------------------
// Kernel 4: context[b][n] = sum_s attn[b][s] * enc[b][s][n]
// ---------------------------------------------------------------------------
#define SCH 32
__global__ __launch_bounds__(256)
void context_kernel(const float* __restrict__ attn, const float* __restrict__ enc,
                    float* __restrict__ ctx) {
    int b  = blockIdx.y;
    int s0 = blockIdx.x * (S / SCH);
    int n4 = threadIdx.x;
    const float4* ep = (const float4*)(enc + ((size_t)b * S + s0) * N);
    float4 acc = {0.f, 0.f, 0.f, 0.f};
    for (int s = 0; s < S / SCH; ++s) {
        float a = attn[(size_t)b * S + s0 + s];
        float4 ev = ep[(size_t)s * (N / 4) + n4];
        acc.x += a * ev.x; acc.y += a * ev.y;
        acc.z += a * ev.z; acc.w += a * ev.w;
    }
    float* cp = ctx + (size_t)b * N + n4 * 4;
    atomicAdd(cp + 0, acc.x);
    atomicAdd(cp + 1, acc.y);
    atomicAdd(cp + 2, acc.z);
    atomicAdd(cp + 3, acc.w);
}

// ---------------------------------------------------------------------------
extern "C" void kernel_launch(void* const* d_in, const int* in_sizes, int n_in,
                              void* d_out, int out_size, void* d_ws, size_t ws_size,
                              hipStream_t stream) {
    const float* dec  = (const float*)d_in[0];
    const float* enc  = (const float*)d_in[1];
    const int*   lens = (const int*)  d_in[2];
    const float* cov  = (const float*)d_in[3];
    const float* Wh   = (const float*)d_in[4];
    const float* bh   = (const float*)d_in[5];
    const float* Ws   = (const float*)d_in[6];
    const float* bs   = (const float*)d_in[7];
    const float* wc   = (const float*)d_in[8];
    const float* v    = (const float*)d_in[9];

    float* out     = (float*)d_out;
    float* ctx     = out;                    // B*N
    float* attn    = out + (size_t)B * N;    // B*S
    float* cov_out = attn + (size_t)B * S;   // B*S

    // workspace layout
    size_t off_e    = (size_t)B * N * 4;                 // after dec_feats
    size_t off_encb = off_e + (size_t)B * S * 4;         // after e
    size_t off_whb  = off_encb + (size_t)B * S * N * 2;  // after enc_bf16
    size_t need     = off_whb + (size_t)N * N * 2;

    float* dec_feats = (float*)d_ws;
    float* e         = (float*)((char*)d_ws + off_e);

    hipMemsetAsync(e, 0, (size_t)B * S * sizeof(float), stream);
    hipMemsetAsync(ctx, 0, (size_t)B * N * sizeof(float), stream);

    dec_feats_kernel<<<(B * N) / 256, 256, 0, stream>>>(dec, Ws, bs, dec_feats);

    if (ws_size >= need) {
        // fast path: one-time bf16 conversion + global_load_lds GEMM
        short* encb = (short*)((char*)d_ws + off_encb);
        short* whb  = (short*)((char*)d_ws + off_whb);
        cvt_bf16_kernel<<<2048, 256, 0, stream>>>(enc, encb, (size_t)B * S * N / 8);
        cvt_bf16_kernel<<<512, 256, 0, stream>>>(Wh, whb, (size_t)N * N / 8);
        score_mfma_bf16_kernel<<<(B * S / BR) * (N / BM), 256, 0, stream>>>(
            encb, whb, bh, dec_feats, cov, wc, v, e);
    } else {
        score_mfma_kernel<<<(B * S / BR) * (N / BM), 256, 0, stream>>>(
            enc, Wh, bh, dec_feats, cov, wc, v, e);
    }

    softmax_kernel<<<B, 256, 0, stream>>>(e, lens, cov, attn, cov_out);
    context_kernel<<<dim3(SCH, B), 256, 0, stream>>>(attn, enc, ctx);
}

// Round 4
// 1238.557 us; speedup vs baseline: 1.1235x; 1.1235x over previous
//
#include <hip/hip_runtime.h>
#include <math.h>

#define B 32
#define S 4096
#define N 1024

typedef short short8 __attribute__((ext_vector_type(8)));
typedef short short4v __attribute__((ext_vector_type(4)));
typedef float float4v __attribute__((ext_vector_type(4)));

__device__ inline short f2bf(float f) {
    unsigned u = __builtin_bit_cast(unsigned, f);
    u += 0x7fffu + ((u >> 16) & 1u);   // RNE
    return (short)(u >> 16);
}

// async global->LDS DMA, 16 B per lane. LDS dest wave-uniform + lane*16 linear.
__device__ __forceinline__ void load_lds16(const void* g, void* l) {
    __builtin_amdgcn_global_load_lds(
        (const __attribute__((address_space(1))) void*)g,
        (__attribute__((address_space(3))) void*)l, 16, 0, 0);
}

// ---------------------------------------------------------------------------
// Kernel 1: dec_feats[b][m] = dot(dec_in_state[b], Ws[m]) + bs[m]
// ---------------------------------------------------------------------------
__global__ __launch_bounds__(256)
void dec_feats_kernel(const float* __restrict__ dec, const float* __restrict__ Ws,
                      const float* __restrict__ bs, float* __restrict__ dec_feats) {
    int t = blockIdx.x * blockDim.x + threadIdx.x;
    int b = t & (B - 1);
    int m = t >> 5;
    const float4* drow = (const float4*)(dec + (size_t)b * N);
    const float4* wrow = (const float4*)(Ws + (size_t)m * N);
    float acc = 0.f;
    for (int n4 = 0; n4 < N / 4; ++n4) {
        float4 a = drow[n4];
        float4 w = wrow[n4];
        acc += a.x * w.x + a.y * w.y + a.z * w.z + a.w * w.w;
    }
    dec_feats[(size_t)b * N + m] = acc + bs[m];
}

// ---------------------------------------------------------------------------
// Kernel 1b: fp32 -> bf16 one-time conversion (memory-bound, grid-stride).
// ---------------------------------------------------------------------------
__global__ __launch_bounds__(256)
void cvt_bf16_kernel(const float* __restrict__ src, short* __restrict__ dst,
                     size_t n8) {
    size_t i = (size_t)blockIdx.x * 256 + threadIdx.x;
    size_t stride = (size_t)gridDim.x * 256;
    for (; i < n8; i += stride) {
        const float4v* s = (const float4v*)(src + i * 8);
        float4v a = s[0], b = s[1];
        short8 o = { f2bf(a.x), f2bf(a.y), f2bf(a.z), f2bf(a.w),
                     f2bf(b.x), f2bf(b.y), f2bf(b.z), f2bf(b.w) };
        *(short8*)(dst + i * 8) = o;
    }
}

// ---------------------------------------------------------------------------
// Kernel 2a: 256x256 8-phase bf16 MFMA GEMM (T1+T2+T3+T4+T5) with fused
// tanh·v epilogue.
//
// Tile 256(rows)x256(m), BK=64 split as two K-halves [256][32]. 8 waves
// (2M x 4N), each owning 128x64. LDS 128 KiB: 2 slots x {A,B} x 2 K-halves.
//
// Swizzle (T2, rule #21): logical granule g of row R sits at physical
// g ^ ((R>>1)&3). Staged by pre-swizzling the per-lane GLOBAL source addr
// (LDS dest stays linear for global_load_lds); reads apply the same XOR.
//
// Schedule (audited r3): phase = {ds_read quadrant | STAGE freed half-tile |
// barrier | lgkmcnt(0) | 16 MFMA (setprio) | [vmcnt(8) odd phases] | barrier}.
// Per-wave FIFO: vmcnt(8) at P1/P3/P5/P7 completes exactly the 2 half-tiles
// the phase-after-next needs; barrier converts per-wave completion to
// cross-wave visibility. lgkmcnt(0)+closing-barrier makes restage WAR-safe.
// Never drains vmcnt to 0 inside the loop (T4).
// ---------------------------------------------------------------------------
#define REGION_A(slot, hk) ((slot)*16384 + (hk)*8192)
#define REGION_B(slot, hk) (32768 + (slot)*16384 + (hk)*8192)

__global__ __launch_bounds__(512, 2)
void score_mfma8_kernel(const short* __restrict__ encb, const short* __restrict__ whb,
                        const float* __restrict__ bh, const float* __restrict__ dec_feats,
                        const float* __restrict__ cov, const float* __restrict__ wc,
                        const float* __restrict__ v, float* __restrict__ e) {
    __shared__ short lds[65536];   // 128 KiB

    // T1: bijective XCD swizzle (2048 % 8 == 0). Each XCD gets 64 row-tiles
    // x all 4 m-tiles contiguously: B-panels L2-resident, A read once/XCD.
    unsigned bid = blockIdx.x;
    unsigned c = (bid & 7u) * 256u + (bid >> 3);
    int rt = (int)(c >> 2), mtile = (int)(c & 3u);
    int r0 = rt * 256, m0 = mtile * 256;

    int t = threadIdx.x, lane = t & 63, w = t >> 6;
    int wm_ = w >> 2, wn_ = w & 3;         // 2 x 4 wave grid
    int cq = lane >> 4, cm = lane & 15;

    // staging source (pre-swizzled global address, rule #21)
    int srow = lane >> 2;                              // 0..15 within chunk
    int sg = (lane & 3) ^ ((lane >> 3) & 3);           // logical granule
    const short* aS0 = encb + (size_t)(r0 + w * 16 + srow) * N + sg * 8;
    const short* aS1 = aS0 + (size_t)128 * N;
    const short* bS0 = whb + (size_t)(m0 + w * 16 + srow) * N + sg * 8;
    const short* bS1 = bS0 + (size_t)128 * N;
    const int dc0 = w * 512, dc1 = dc0 + 4096;         // chunk dests (shorts)

    // fragment read offsets (swizzled), loop-invariant
    int aoff[8], boff[4];
#pragma unroll
    for (int f = 0; f < 8; ++f) {
        int R = wm_ * 128 + f * 16 + cm;
        aoff[f] = R * 32 + ((cq ^ ((R >> 1) & 3)) << 3);
    }
#pragma unroll
    for (int j = 0; j < 4; ++j) {
        int R = wn_ * 64 + j * 16 + cm;
        boff[j] = R * 32 + ((cq ^ ((R >> 1) & 3)) << 3);
    }

    float4v acc[8][4];
#pragma unroll
    for (int f = 0; f < 8; ++f)
#pragma unroll
        for (int j = 0; j < 4; ++j) acc[f][j] = (float4v){0.f, 0.f, 0.f, 0.f};

#define STAGE(srcp0, srcp1, region, colElem) do {                         \
        int _cc = (colElem) & (N - 1);                                    \
        load_lds16((srcp0) + _cc, &lds[(region) + dc0]);                  \
        load_lds16((srcp1) + _cc, &lds[(region) + dc1]);                  \
    } while (0)

    // Prologue: kt0 (slot0, both halves) + kt1 half0 (slot1). 12 loads.
    STAGE(aS0, aS1, REGION_A(0, 0), 0);
    STAGE(bS0, bS1, REGION_B(0, 0), 0);
    STAGE(aS0, aS1, REGION_A(0, 1), 32);
    STAGE(bS0, bS1, REGION_B(0, 1), 32);
    STAGE(aS0, aS1, REGION_A(1, 0), 64);
    STAGE(bS0, bS1, REGION_B(1, 0), 64);
    asm volatile("s_waitcnt vmcnt(8)" ::: "memory");   // loads 1-4 (slot0 h0) done
    __builtin_amdgcn_s_barrier();

    short8 bf[4];

#define PHASE(slot, sub, SRC0, SRC1, SREGION, SCOL) do {                      \
        const int hk_ = (sub) >> 1, mh_ = (sub) & 1;                          \
        if (mh_ == 0) {                                                       \
            _Pragma("unroll")                                                 \
            for (int j = 0; j < 4; ++j)                                       \
                bf[j] = *(const short8*)&lds[REGION_B(slot, hk_) + boff[j]];  \
        }                                                                     \
        short8 af[4];                                                         \
        _Pragma("unroll")                                                     \
        for (int f = 0; f < 4; ++f)                                           \
            af[f] = *(const short8*)&lds[REGION_A(slot, hk_) + aoff[mh_ * 4 + f]]; \
        STAGE(SRC0, SRC1, SREGION, SCOL);                                     \
        __builtin_amdgcn_s_barrier();                                         \
        asm volatile("s_waitcnt lgkmcnt(0)" ::: "memory");                    \
        __builtin_amdgcn_sched_barrier(0);                                    \
        __builtin_amdgcn_s_setprio(1);                                        \
        _Pragma("unroll")                                                     \
        for (int f = 0; f < 4; ++f)                                           \
            _Pragma("unroll")                                                 \
            for (int j = 0; j < 4; ++j)                                       \
                acc[mh_ * 4 + f][j] = __builtin_amdgcn_mfma_f32_16x16x32_bf16(\
                    af[f], bf[j], acc[mh_ * 4 + f][j], 0, 0, 0);              \
        __builtin_amdgcn_s_setprio(0);                                        \
        if (mh_ == 1) asm volatile("s_waitcnt vmcnt(8)" ::: "memory");        \
        __builtin_amdgcn_s_barrier();                                         \
    } while (0)

#pragma unroll 1
    for (int i = 0; i < 8; ++i) {        // 8 iters x 2 K-tiles = K=1024
        int kb = i * 128;
        PHASE(0, 0, aS0, aS1, REGION_A(1, 1), kb + 96);
        PHASE(0, 1, bS0, bS1, REGION_B(1, 1), kb + 96);
        PHASE(0, 2, aS0, aS1, REGION_A(0, 0), kb + 128);
        PHASE(0, 3, bS0, bS1, REGION_B(0, 0), kb + 128);
        PHASE(1, 0, aS0, aS1, REGION_A(0, 1), kb + 160);
        PHASE(1, 1, bS0, bS1, REGION_B(0, 1), kb + 160);
        PHASE(1, 2, aS0, aS1, REGION_A(1, 0), kb + 192);
        PHASE(1, 3, bS0, bS1, REGION_B(1, 0), kb + 192);
    }
    asm volatile("s_waitcnt vmcnt(0)" ::: "memory");
#undef PHASE
#undef STAGE

    // Epilogue. C/D layout (verified): col(m) = lane&15, row = cq*4 + reg.
    int bidx = r0 >> 12;
    const float* df = dec_feats + ((size_t)bidx << 10);

    float basej[4], wcj[4], vj[4];
#pragma unroll
    for (int j = 0; j < 4; ++j) {
        int m = m0 + wn_ * 64 + j * 16 + cm;
        basej[j] = bh[m] + df[m];
        wcj[j]   = wc[m];
        vj[j]    = v[m];
    }

#pragma unroll
    for (int f = 0; f < 8; ++f) {
        int rbase = r0 + wm_ * 128 + f * 16 + cq * 4;
        float4v cvv = *(const float4v*)&cov[rbase];
        float cv[4] = {cvv.x, cvv.y, cvv.z, cvv.w};
        float rs[4] = {0.f, 0.f, 0.f, 0.f};
#pragma unroll
        for (int j = 0; j < 4; ++j) {
#pragma unroll
            for (int reg = 0; reg < 4; ++reg) {
                float val = acc[f][j][reg] + basej[j] + cv[reg] * wcj[j];
                val = fminf(fmaxf(val, -30.f), 30.f);
                float texp = __expf(2.f * val);
                float th = (texp - 1.f) * __builtin_amdgcn_rcpf(texp + 1.f);
                rs[reg] += th * vj[j];
            }
        }
#pragma unroll
        for (int reg = 0; reg < 4; ++reg) {
            float p = rs[reg];
            p += __shfl_xor(p, 1);
            p += __shfl_xor(p, 2);
            p += __shfl_xor(p, 4);
            p += __shfl_xor(p, 8);
            if (cm == 0) atomicAdd(&e[rbase + reg], p);
        }
    }
}

// ---------------------------------------------------------------------------
// Kernel 2b (fallback if workspace too small): fp32-staging MFMA kernel.
// ---------------------------------------------------------------------------
#define BR 128
#define BM 128
#define BK 64
#define LDK (BK + 8)

__global__ __launch_bounds__(256)
void score_mfma_kernel(const float* __restrict__ enc, const float* __restrict__ Wh,
                       const float* __restrict__ bh, const float* __restrict__ dec_feats,
                       const float* __restrict__ cov, const float* __restrict__ wc,
                       const float* __restrict__ v, float* __restrict__ e) {
    __shared__ short As[BR][LDK];
    __shared__ short Bs[BM][LDK];

    unsigned h   = blockIdx.x;
    unsigned xcd = h & 7u;
    unsigned mt  = (h >> 3) & 7u;
    unsigned g   = h >> 6;
    int r0 = (int)(xcd + 8u * g) * BR;
    int m0 = (int)mt * BM;

    int t    = threadIdx.x;
    int lane = t & 63;
    int w    = t >> 6;
    int wr   = (w >> 1) * 64;
    int wm   = (w & 1) * 64;
    int cq   = lane >> 4;
    int cm   = lane & 15;

    float4v acc[4][4];
#pragma unroll
    for (int i = 0; i < 4; ++i)
#pragma unroll
        for (int j = 0; j < 4; ++j) acc[i][j] = (float4v){0.f, 0.f, 0.f, 0.f};

    int srow = t >> 4;
    int scol = (t & 15) * 4;

    for (int k0 = 0; k0 < N; k0 += BK) {
#pragma unroll
        for (int p = 0; p < 8; ++p) {
            int row = p * 16 + srow;
            float4v a = *(const float4v*)(enc + (size_t)(r0 + row) * N + k0 + scol);
            short4v ap = { f2bf(a.x), f2bf(a.y), f2bf(a.z), f2bf(a.w) };
            *(short4v*)&As[row][scol] = ap;
            float4v bq = *(const float4v*)(Wh + (size_t)(m0 + row) * N + k0 + scol);
            short4v bp = { f2bf(bq.x), f2bf(bq.y), f2bf(bq.z), f2bf(bq.w) };
            *(short4v*)&Bs[row][scol] = bp;
        }
        __syncthreads();
#pragma unroll
        for (int ks = 0; ks < BK; ks += 32) {
            short8 af[4], bfr[4];
#pragma unroll
            for (int i = 0; i < 4; ++i)
                af[i] = *(const short8*)&As[wr + i * 16 + cm][ks + cq * 8];
#pragma unroll
            for (int j = 0; j < 4; ++j)
                bfr[j] = *(const short8*)&Bs[wm + j * 16 + cm][ks + cq * 8];
#pragma unroll
            for (int i = 0; i < 4; ++i)
#pragma unroll
                for (int j = 0; j < 4; ++j)
                    acc[i][j] = __builtin_amdgcn_mfma_f32_16x16x32_bf16(
                        af[i], bfr[j], acc[i][j], 0, 0, 0);
        }
        __syncthreads();
    }

    int b = r0 >> 12;
    const float* df = dec_feats + ((size_t)b << 10);

    float basej[4], wcj[4], vj[4];
#pragma unroll
    for (int j = 0; j < 4; ++j) {
        int m = m0 + wm + j * 16 + cm;
        basej[j] = bh[m] + df[m];
        wcj[j]   = wc[m];
        vj[j]    = v[m];
    }

#pragma unroll
    for (int i = 0; i < 4; ++i) {
        int rbase = r0 + wr + i * 16 + cq * 4;
        float cv[4];
#pragma unroll
        for (int reg = 0; reg < 4; ++reg) cv[reg] = cov[rbase + reg];
        float rs[4] = {0.f, 0.f, 0.f, 0.f};
#pragma unroll
        for (int j = 0; j < 4; ++j) {
#pragma unroll
            for (int reg = 0; reg < 4; ++reg) {
                float val = acc[i][j][reg] + basej[j] + cv[reg] * wcj[j];
                val = fminf(fmaxf(val, -30.f), 30.f);
                float texp = __expf(2.f * val);
                float th = (texp - 1.f) * __builtin_amdgcn_rcpf(texp + 1.f);
                rs[reg] += th * vj[j];
            }
        }
#pragma unroll
        for (int reg = 0; reg < 4; ++reg) {
            float p = rs[reg];
            p += __shfl_xor(p, 1);
            p += __shfl_xor(p, 2);
            p += __shfl_xor(p, 4);
            p += __shfl_xor(p, 8);
            if (cm == 0) atomicAdd(&e[rbase + reg], p);
        }
    }
}

// ---------------------------------------------------------------------------
// Kernel 3: masked softmax + coverage update. One block per batch row.
// ---------------------------------------------------------------------------
__global__ __launch_bounds__(256)
void softmax_kernel(const float* __restrict__ e, const int* __restrict__ lens,
                    const float* __restrict__ cov,
                    float* __restrict__ attn, float* __restrict__ cov_out) {
    int b = blockIdx.x;
    int len = lens[b];
    const float* eb = e + (size_t)b * S;
    __shared__ float red[256];
    int t = threadIdx.x;

    float mx = -INFINITY;
    for (int s = t; s < S; s += 256)
        if (s < len) mx = fmaxf(mx, eb[s]);
    red[t] = mx; __syncthreads();
    for (int off = 128; off > 0; off >>= 1) {
        if (t < off) red[t] = fmaxf(red[t], red[t + off]);
        __syncthreads();
    }
    mx = red[0]; __syncthreads();

    float sum = 0.f;
    for (int s = t; s < S; s += 256)
        if (s < len) sum += __expf(eb[s] - mx);
    red[t] = sum; __syncthreads();
    for (int off = 128; off > 0; off >>= 1) {
        if (t < off) red[t] += red[t + off];
        __syncthreads();
    }
    float inv = 1.f / red[0];

    for (int s = t; s < S; s += 256) {
        float a = (s < len) ? __expf(eb[s] - mx) * inv : 0.f;
        attn[(size_t)b * S + s] = a;
        cov_out[(size_t)b * S + s] = cov[(size_t)b * S + s] + a;
    }
}

// ---------------------------------------------------------------------------
// Kernel 4: context[b][n] = sum_s attn[b][s] * enc[b][s][n]
// ---------------------------------------------------------------------------
#define SCH 32
__global__ __launch_bounds__(256)
void context_kernel(const float* __restrict__ attn, const float* __restrict__ enc,
                    float* __restrict__ ctx) {
    int b  = blockIdx.y;
    int s0 = blockIdx.x * (S / SCH);
    int n4 = threadIdx.x;
    const float4* ep = (const float4*)(enc + ((size_t)b * S + s0) * N);
    float4 acc = {0.f, 0.f, 0.f, 0.f};
    for (int s = 0; s < S / SCH; ++s) {
        float a = attn[(size_t)b * S + s0 + s];
        float4 ev = ep[(size_t)s * (N / 4) + n4];
        acc.x += a * ev.x; acc.y += a * ev.y;
        acc.z += a * ev.z; acc.w += a * ev.w;
    }
    float* cp = ctx + (size_t)b * N + n4 * 4;
    atomicAdd(cp + 0, acc.x);
    atomicAdd(cp + 1, acc.y);
    atomicAdd(cp + 2, acc.z);
    atomicAdd(cp + 3, acc.w);
}

// ---------------------------------------------------------------------------
extern "C" void kernel_launch(void* const* d_in, const int* in_sizes, int n_in,
                              void* d_out, int out_size, void* d_ws, size_t ws_size,
                              hipStream_t stream) {
    const float* dec  = (const float*)d_in[0];
    const float* enc  = (const float*)d_in[1];
    const int*   lens = (const int*)  d_in[2];
    const float* cov  = (const float*)d_in[3];
    const float* Wh   = (const float*)d_in[4];
    const float* bh   = (const float*)d_in[5];
    const float* Ws   = (const float*)d_in[6];
    const float* bs   = (const float*)d_in[7];
    const float* wc   = (const float*)d_in[8];
    const float* v    = (const float*)d_in[9];

    float* out     = (float*)d_out;
    float* ctx     = out;                    // B*N
    float* attn    = out + (size_t)B * N;    // B*S
    float* cov_out = attn + (size_t)B * S;   // B*S

    size_t off_e    = (size_t)B * N * 4;
    size_t off_encb = off_e + (size_t)B * S * 4;
    size_t off_whb  = off_encb + (size_t)B * S * N * 2;
    size_t need     = off_whb + (size_t)N * N * 2;

    float* dec_feats = (float*)d_ws;
    float* e         = (float*)((char*)d_ws + off_e);

    hipMemsetAsync(e, 0, (size_t)B * S * sizeof(float), stream);
    hipMemsetAsync(ctx, 0, (size_t)B * N * sizeof(float), stream);

    dec_feats_kernel<<<(B * N) / 256, 256, 0, stream>>>(dec, Ws, bs, dec_feats);

    if (ws_size >= need) {
        short* encb = (short*)((char*)d_ws + off_encb);
        short* whb  = (short*)((char*)d_ws + off_whb);
        cvt_bf16_kernel<<<2048, 256, 0, stream>>>(enc, encb, (size_t)B * S * N / 8);
        cvt_bf16_kernel<<<512, 256, 0, stream>>>(Wh, whb, (size_t)N * N / 8);
        score_mfma8_kernel<<<2048, 512, 0, stream>>>(
            encb, whb, bh, dec_feats, cov, wc, v, e);
    } else {
        score_mfma_kernel<<<(B * S / BR) * (N / BM), 256, 0, stream>>>(
            enc, Wh, bh, dec_feats, cov, wc, v, e);
    }

    softmax_kernel<<<B, 256, 0, stream>>>(e, lens, cov, attn, cov_out);
    context_kernel<<<dim3(SCH, B), 256, 0, stream>>>(attn, enc, ctx);
}

// Round 5
// 1233.001 us; speedup vs baseline: 1.1286x; 1.0045x over previous
//
#include <hip/hip_runtime.h>
#include <math.h>

#define B 32
#define S 4096
#define N 1024

typedef short short8 __attribute__((ext_vector_type(8)));
typedef short short4v __attribute__((ext_vector_type(4)));
typedef float float4v __attribute__((ext_vector_type(4)));

__device__ inline short f2bf(float f) {
    unsigned u = __builtin_bit_cast(unsigned, f);
    u += 0x7fffu + ((u >> 16) & 1u);   // RNE
    return (short)(u >> 16);
}

// async global->LDS DMA, 16 B per lane. LDS dest wave-uniform + lane*16 linear.
__device__ __forceinline__ void load_lds16(const void* g, void* l) {
    __builtin_amdgcn_global_load_lds(
        (const __attribute__((address_space(1))) void*)g,
        (__attribute__((address_space(3))) void*)l, 16, 0, 0);
}

// ---------------------------------------------------------------------------
// Kernel 1: dec_feats[b][m] = dot(dec_in_state[b], Ws[m]) + bs[m]
// ---------------------------------------------------------------------------
__global__ __launch_bounds__(256)
void dec_feats_kernel(const float* __restrict__ dec, const float* __restrict__ Ws,
                      const float* __restrict__ bs, float* __restrict__ dec_feats) {
    int t = blockIdx.x * blockDim.x + threadIdx.x;
    int b = t & (B - 1);
    int m = t >> 5;
    const float4* drow = (const float4*)(dec + (size_t)b * N);
    const float4* wrow = (const float4*)(Ws + (size_t)m * N);
    float acc = 0.f;
    for (int n4 = 0; n4 < N / 4; ++n4) {
        float4 a = drow[n4];
        float4 w = wrow[n4];
        acc += a.x * w.x + a.y * w.y + a.z * w.z + a.w * w.w;
    }
    dec_feats[(size_t)b * N + m] = acc + bs[m];
}

// ---------------------------------------------------------------------------
// Kernel 1b: fp32 -> bf16 one-time conversion (memory-bound, grid-stride).
// ---------------------------------------------------------------------------
__global__ __launch_bounds__(256)
void cvt_bf16_kernel(const float* __restrict__ src, short* __restrict__ dst,
                     size_t n8) {
    size_t i = (size_t)blockIdx.x * 256 + threadIdx.x;
    size_t stride = (size_t)gridDim.x * 256;
    for (; i < n8; i += stride) {
        const float4v* s = (const float4v*)(src + i * 8);
        float4v a = s[0], b = s[1];
        short8 o = { f2bf(a.x), f2bf(a.y), f2bf(a.z), f2bf(a.w),
                     f2bf(b.x), f2bf(b.y), f2bf(b.z), f2bf(b.w) };
        *(short8*)(dst + i * 8) = o;
    }
}

// ---------------------------------------------------------------------------
// Kernel 2a: 256x256 8-phase bf16 MFMA GEMM (T1+T2+T3+T4+T5) with fused
// tanh·v epilogue. Schedule verified on-chip r4: 362 µs, MfmaUtil 34,
// SQ_LDS_BANK_CONFLICT 0, absmax 0.0039. DO NOT touch sync structure
// without re-running the r3 FIFO audit.
// ---------------------------------------------------------------------------
#define REGION_A(slot, hk) ((slot)*16384 + (hk)*8192)
#define REGION_B(slot, hk) (32768 + (slot)*16384 + (hk)*8192)

__global__ __launch_bounds__(512, 2)
void score_mfma8_kernel(const short* __restrict__ encb, const short* __restrict__ whb,
                        const float* __restrict__ bh, const float* __restrict__ dec_feats,
                        const float* __restrict__ cov, const float* __restrict__ wc,
                        const float* __restrict__ v, float* __restrict__ e) {
    __shared__ short lds[65536];   // 128 KiB

    // T1: bijective XCD swizzle (2048 % 8 == 0). 4 m-tiles of a row-tile are
    // consecutive on one XCD: A-panel L2-resident across them, whb (2 MB)
    // L2-resident outright.
    unsigned bid = blockIdx.x;
    unsigned c = (bid & 7u) * 256u + (bid >> 3);
    int rt = (int)(c >> 2), mtile = (int)(c & 3u);
    int r0 = rt * 256, m0 = mtile * 256;

    int t = threadIdx.x, lane = t & 63, w = t >> 6;
    int wm_ = w >> 2, wn_ = w & 3;         // 2 x 4 wave grid
    int cq = lane >> 4, cm = lane & 15;

    // staging source (pre-swizzled global address, rule #21)
    int srow = lane >> 2;                              // 0..15 within chunk
    int sg = (lane & 3) ^ ((lane >> 3) & 3);           // logical granule
    const short* aS0 = encb + (size_t)(r0 + w * 16 + srow) * N + sg * 8;
    const short* aS1 = aS0 + (size_t)128 * N;
    const short* bS0 = whb + (size_t)(m0 + w * 16 + srow) * N + sg * 8;
    const short* bS1 = bS0 + (size_t)128 * N;
    const int dc0 = w * 512, dc1 = dc0 + 4096;         // chunk dests (shorts)

    // fragment read offsets (swizzled), loop-invariant
    int aoff[8], boff[4];
#pragma unroll
    for (int f = 0; f < 8; ++f) {
        int R = wm_ * 128 + f * 16 + cm;
        aoff[f] = R * 32 + ((cq ^ ((R >> 1) & 3)) << 3);
    }
#pragma unroll
    for (int j = 0; j < 4; ++j) {
        int R = wn_ * 64 + j * 16 + cm;
        boff[j] = R * 32 + ((cq ^ ((R >> 1) & 3)) << 3);
    }

    float4v acc[8][4];
#pragma unroll
    for (int f = 0; f < 8; ++f)
#pragma unroll
        for (int j = 0; j < 4; ++j) acc[f][j] = (float4v){0.f, 0.f, 0.f, 0.f};

#define STAGE(srcp0, srcp1, region, colElem) do {                         \
        int _cc = (colElem) & (N - 1);                                    \
        load_lds16((srcp0) + _cc, &lds[(region) + dc0]);                  \
        load_lds16((srcp1) + _cc, &lds[(region) + dc1]);                  \
    } while (0)

    // Prologue: kt0 (slot0, both halves) + kt1 half0 (slot1). 12 loads.
    STAGE(aS0, aS1, REGION_A(0, 0), 0);
    STAGE(bS0, bS1, REGION_B(0, 0), 0);
    STAGE(aS0, aS1, REGION_A(0, 1), 32);
    STAGE(bS0, bS1, REGION_B(0, 1), 32);
    STAGE(aS0, aS1, REGION_A(1, 0), 64);
    STAGE(bS0, bS1, REGION_B(1, 0), 64);
    asm volatile("s_waitcnt vmcnt(8)" ::: "memory");   // loads 1-4 (slot0 h0) done
    __builtin_amdgcn_s_barrier();

    short8 bf[4];

#define PHASE(slot, sub, SRC0, SRC1, SREGION, SCOL) do {                      \
        const int hk_ = (sub) >> 1, mh_ = (sub) & 1;                          \
        if (mh_ == 0) {                                                       \
            _Pragma("unroll")                                                 \
            for (int j = 0; j < 4; ++j)                                       \
                bf[j] = *(const short8*)&lds[REGION_B(slot, hk_) + boff[j]];  \
        }                                                                     \
        short8 af[4];                                                         \
        _Pragma("unroll")                                                     \
        for (int f = 0; f < 4; ++f)                                           \
            af[f] = *(const short8*)&lds[REGION_A(slot, hk_) + aoff[mh_ * 4 + f]]; \
        STAGE(SRC0, SRC1, SREGION, SCOL);                                     \
        __builtin_amdgcn_s_barrier();                                         \
        asm volatile("s_waitcnt lgkmcnt(0)" ::: "memory");                    \
        __builtin_amdgcn_sched_barrier(0);                                    \
        __builtin_amdgcn_s_setprio(1);                                        \
        _Pragma("unroll")                                                     \
        for (int f = 0; f < 4; ++f)                                           \
            _Pragma("unroll")                                                 \
            for (int j = 0; j < 4; ++j)                                       \
                acc[mh_ * 4 + f][j] = __builtin_amdgcn_mfma_f32_16x16x32_bf16(\
                    af[f], bf[j], acc[mh_ * 4 + f][j], 0, 0, 0);              \
        __builtin_amdgcn_s_setprio(0);                                        \
        if (mh_ == 1) asm volatile("s_waitcnt vmcnt(8)" ::: "memory");        \
        __builtin_amdgcn_s_barrier();                                         \
    } while (0)

#pragma unroll 1
    for (int i = 0; i < 8; ++i) {        // 8 iters x 2 K-tiles = K=1024
        int kb = i * 128;
        PHASE(0, 0, aS0, aS1, REGION_A(1, 1), kb + 96);
        PHASE(0, 1, bS0, bS1, REGION_B(1, 1), kb + 96);
        PHASE(0, 2, aS0, aS1, REGION_A(0, 0), kb + 128);
        PHASE(0, 3, bS0, bS1, REGION_B(0, 0), kb + 128);
        PHASE(1, 0, aS0, aS1, REGION_A(0, 1), kb + 160);
        PHASE(1, 1, bS0, bS1, REGION_B(0, 1), kb + 160);
        PHASE(1, 2, aS0, aS1, REGION_A(1, 0), kb + 192);
        PHASE(1, 3, bS0, bS1, REGION_B(1, 0), kb + 192);
    }
    asm volatile("s_waitcnt vmcnt(0)" ::: "memory");
#undef PHASE
#undef STAGE

    // Epilogue. C/D layout (verified): col(m) = lane&15, row = cq*4 + reg.
    // tanh(x) = 1 - 2/(exp2(2*log2e*x)+1)  — algebraically == (t-1)/(t+1).
    int bidx = r0 >> 12;
    const float* df = dec_feats + ((size_t)bidx << 10);

    float basej[4], wcj[4], vj[4];
#pragma unroll
    for (int j = 0; j < 4; ++j) {
        int m = m0 + wn_ * 64 + j * 16 + cm;
        basej[j] = bh[m] + df[m];
        wcj[j]   = wc[m];
        vj[j]    = v[m];
    }

#pragma unroll
    for (int f = 0; f < 8; ++f) {
        int rbase = r0 + wm_ * 128 + f * 16 + cq * 4;
        float4v cvv = *(const float4v*)&cov[rbase];
        float cv[4] = {cvv.x, cvv.y, cvv.z, cvv.w};
        float rs[4] = {0.f, 0.f, 0.f, 0.f};
#pragma unroll
        for (int j = 0; j < 4; ++j) {
#pragma unroll
            for (int reg = 0; reg < 4; ++reg) {
                float val = acc[f][j][reg] + basej[j] + cv[reg] * wcj[j];
                val = fminf(fmaxf(val, -15.f), 15.f);           // tanh sat @ fp32
                float t2 = __builtin_amdgcn_exp2f(val * 2.8853900817779268f);
                float r  = __builtin_amdgcn_rcpf(t2 + 1.f);
                float th = fmaf(-2.f, r, 1.f);
                rs[reg] = fmaf(th, vj[j], rs[reg]);
            }
        }
#pragma unroll
        for (int reg = 0; reg < 4; ++reg) {
            float p = rs[reg];
            p += __shfl_xor(p, 1);
            p += __shfl_xor(p, 2);
            p += __shfl_xor(p, 4);
            p += __shfl_xor(p, 8);
            if (cm == 0) atomicAdd(&e[rbase + reg], p);   // same-XCD only (T1)
        }
    }
}

// ---------------------------------------------------------------------------
// Kernel 2b (fallback if workspace too small): fp32-staging MFMA kernel.
// ---------------------------------------------------------------------------
#define BR 128
#define BM 128
#define BK 64
#define LDK (BK + 8)

__global__ __launch_bounds__(256)
void score_mfma_kernel(const float* __restrict__ enc, const float* __restrict__ Wh,
                       const float* __restrict__ bh, const float* __restrict__ dec_feats,
                       const float* __restrict__ cov, const float* __restrict__ wc,
                       const float* __restrict__ v, float* __restrict__ e) {
    __shared__ short As[BR][LDK];
    __shared__ short Bs[BM][LDK];

    unsigned h   = blockIdx.x;
    unsigned xcd = h & 7u;
    unsigned mt  = (h >> 3) & 7u;
    unsigned g   = h >> 6;
    int r0 = (int)(xcd + 8u * g) * BR;
    int m0 = (int)mt * BM;

    int t    = threadIdx.x;
    int lane = t & 63;
    int w    = t >> 6;
    int wr   = (w >> 1) * 64;
    int wm   = (w & 1) * 64;
    int cq   = lane >> 4;
    int cm   = lane & 15;

    float4v acc[4][4];
#pragma unroll
    for (int i = 0; i < 4; ++i)
#pragma unroll
        for (int j = 0; j < 4; ++j) acc[i][j] = (float4v){0.f, 0.f, 0.f, 0.f};

    int srow = t >> 4;
    int scol = (t & 15) * 4;

    for (int k0 = 0; k0 < N; k0 += BK) {
#pragma unroll
        for (int p = 0; p < 8; ++p) {
            int row = p * 16 + srow;
            float4v a = *(const float4v*)(enc + (size_t)(r0 + row) * N + k0 + scol);
            short4v ap = { f2bf(a.x), f2bf(a.y), f2bf(a.z), f2bf(a.w) };
            *(short4v*)&As[row][scol] = ap;
            float4v bq = *(const float4v*)(Wh + (size_t)(m0 + row) * N + k0 + scol);
            short4v bp = { f2bf(bq.x), f2bf(bq.y), f2bf(bq.z), f2bf(bq.w) };
            *(short4v*)&Bs[row][scol] = bp;
        }
        __syncthreads();
#pragma unroll
        for (int ks = 0; ks < BK; ks += 32) {
            short8 af[4], bfr[4];
#pragma unroll
            for (int i = 0; i < 4; ++i)
                af[i] = *(const short8*)&As[wr + i * 16 + cm][ks + cq * 8];
#pragma unroll
            for (int j = 0; j < 4; ++j)
                bfr[j] = *(const short8*)&Bs[wm + j * 16 + cm][ks + cq * 8];
#pragma unroll
            for (int i = 0; i < 4; ++i)
#pragma unroll
                for (int j = 0; j < 4; ++j)
                    acc[i][j] = __builtin_amdgcn_mfma_f32_16x16x32_bf16(
                        af[i], bfr[j], acc[i][j], 0, 0, 0);
        }
        __syncthreads();
    }

    int b = r0 >> 12;
    const float* df = dec_feats + ((size_t)b << 10);

    float basej[4], wcj[4], vj[4];
#pragma unroll
    for (int j = 0; j < 4; ++j) {
        int m = m0 + wm + j * 16 + cm;
        basej[j] = bh[m] + df[m];
        wcj[j]   = wc[m];
        vj[j]    = v[m];
    }

#pragma unroll
    for (int i = 0; i < 4; ++i) {
        int rbase = r0 + wr + i * 16 + cq * 4;
        float cv[4];
#pragma unroll
        for (int reg = 0; reg < 4; ++reg) cv[reg] = cov[rbase + reg];
        float rs[4] = {0.f, 0.f, 0.f, 0.f};
#pragma unroll
        for (int j = 0; j < 4; ++j) {
#pragma unroll
            for (int reg = 0; reg < 4; ++reg) {
                float val = acc[i][j][reg] + basej[j] + cv[reg] * wcj[j];
                val = fminf(fmaxf(val, -15.f), 15.f);
                float t2 = __builtin_amdgcn_exp2f(val * 2.8853900817779268f);
                float r  = __builtin_amdgcn_rcpf(t2 + 1.f);
                float th = fmaf(-2.f, r, 1.f);
                rs[reg] = fmaf(th, vj[j], rs[reg]);
            }
        }
#pragma unroll
        for (int reg = 0; reg < 4; ++reg) {
            float p = rs[reg];
            p += __shfl_xor(p, 1);
            p += __shfl_xor(p, 2);
            p += __shfl_xor(p, 4);
            p += __shfl_xor(p, 8);
            if (cm == 0) atomicAdd(&e[rbase + reg], p);
        }
    }
}

// ---------------------------------------------------------------------------
// Kernel 3: masked softmax + coverage update. One block per batch row.
// ---------------------------------------------------------------------------
__global__ __launch_bounds__(256)
void softmax_kernel(const float* __restrict__ e, const int* __restrict__ lens,
                    const float* __restrict__ cov,
                    float* __restrict__ attn, float* __restrict__ cov_out) {
    int b = blockIdx.x;
    int len = lens[b];
    const float* eb = e + (size_t)b * S;
    __shared__ float red[256];
    int t = threadIdx.x;

    float mx = -INFINITY;
    for (int s = t; s < S; s += 256)
        if (s < len) mx = fmaxf(mx, eb[s]);
    red[t] = mx; __syncthreads();
    for (int off = 128; off > 0; off >>= 1) {
        if (t < off) red[t] = fmaxf(red[t], red[t + off]);
        __syncthreads();
    }
    mx = red[0]; __syncthreads();

    float sum = 0.f;
    for (int s = t; s < S; s += 256)
        if (s < len) sum += __expf(eb[s] - mx);
    red[t] = sum; __syncthreads();
    for (int off = 128; off > 0; off >>= 1) {
        if (t < off) red[t] += red[t + off];
        __syncthreads();
    }
    float inv = 1.f / red[0];

    for (int s = t; s < S; s += 256) {
        float a = (s < len) ? __expf(eb[s] - mx) * inv : 0.f;
        attn[(size_t)b * S + s] = a;
        cov_out[(size_t)b * S + s] = cov[(size_t)b * S + s] + a;
    }
}

// ---------------------------------------------------------------------------
// Kernel 4 (fast path): context via two-stage reduction, ZERO atomics.
// Stage 1: part[b][chunk][n] = sum_{s in chunk} attn[b][s] * enc[b][s][n]
// Stage 2: ctx[b][n] = sum_chunk part[b][chunk][n]
// Replaces 1M cross-XCD contended atomicAdds with 4 MB coalesced writes.
// ---------------------------------------------------------------------------
#define SCH 32
__global__ __launch_bounds__(256)
void context_part_kernel(const float* __restrict__ attn, const float* __restrict__ enc,
                         float* __restrict__ part) {
    int b  = blockIdx.y;
    int ch = blockIdx.x;
    int s0 = ch * (S / SCH);
    int n4 = threadIdx.x;
    const float4* ep = (const float4*)(enc + ((size_t)b * S + s0) * N);
    float4 acc = {0.f, 0.f, 0.f, 0.f};
    for (int s = 0; s < S / SCH; ++s) {
        float a = attn[(size_t)b * S + s0 + s];
        float4 ev = ep[(size_t)s * (N / 4) + n4];
        acc.x += a * ev.x; acc.y += a * ev.y;
        acc.z += a * ev.z; acc.w += a * ev.w;
    }
    *(float4*)&part[((size_t)b * SCH + ch) * N + n4 * 4] = acc;
}

__global__ __launch_bounds__(256)
void context_reduce_kernel(const float* __restrict__ part, float* __restrict__ ctx) {
    int idx = blockIdx.x * 256 + threadIdx.x;   // 0 .. B*N-1
    int b = idx >> 10, n = idx & (N - 1);
    const float* p = part + (size_t)b * SCH * N + n;
    float acc = 0.f;
#pragma unroll
    for (int c = 0; c < SCH; ++c) acc += p[(size_t)c * N];
    ctx[idx] = acc;
}

// ---------------------------------------------------------------------------
// Kernel 4b (fallback): atomic context kernel (needs ctx pre-zeroed).
// ---------------------------------------------------------------------------
__global__ __launch_bounds__(256)
void context_kernel(const float* __restrict__ attn, const float* __restrict__ enc,
                    float* __restrict__ ctx) {
    int b  = blockIdx.y;
    int s0 = blockIdx.x * (S / SCH);
    int n4 = threadIdx.x;
    const float4* ep = (const float4*)(enc + ((size_t)b * S + s0) * N);
    float4 acc = {0.f, 0.f, 0.f, 0.f};
    for (int s = 0; s < S / SCH; ++s) {
        float a = attn[(size_t)b * S + s0 + s];
        float4 ev = ep[(size_t)s * (N / 4) + n4];
        acc.x += a * ev.x; acc.y += a * ev.y;
        acc.z += a * ev.z; acc.w += a * ev.w;
    }
    float* cp = ctx + (size_t)b * N + n4 * 4;
    atomicAdd(cp + 0, acc.x);
    atomicAdd(cp + 1, acc.y);
    atomicAdd(cp + 2, acc.z);
    atomicAdd(cp + 3, acc.w);
}

// ---------------------------------------------------------------------------
extern "C" void kernel_launch(void* const* d_in, const int* in_sizes, int n_in,
                              void* d_out, int out_size, void* d_ws, size_t ws_size,
                              hipStream_t stream) {
    const float* dec  = (const float*)d_in[0];
    const float* enc  = (const float*)d_in[1];
    const int*   lens = (const int*)  d_in[2];
    const float* cov  = (const float*)d_in[3];
    const float* Wh   = (const float*)d_in[4];
    const float* bh   = (const float*)d_in[5];
    const float* Ws   = (const float*)d_in[6];
    const float* bs   = (const float*)d_in[7];
    const float* wc   = (const float*)d_in[8];
    const float* v    = (const float*)d_in[9];

    float* out     = (float*)d_out;
    float* ctx     = out;                    // B*N
    float* attn    = out + (size_t)B * N;    // B*S
    float* cov_out = attn + (size_t)B * S;   // B*S

    size_t off_e    = (size_t)B * N * 4;
    size_t off_encb = off_e + (size_t)B * S * 4;
    size_t off_whb  = off_encb + (size_t)B * S * N * 2;
    size_t off_part = off_whb + (size_t)N * N * 2;
    size_t need     = off_part + (size_t)B * SCH * N * 4;

    float* dec_feats = (float*)d_ws;
    float* e         = (float*)((char*)d_ws + off_e);

    hipMemsetAsync(e, 0, (size_t)B * S * sizeof(float), stream);

    dec_feats_kernel<<<(B * N) / 256, 256, 0, stream>>>(dec, Ws, bs, dec_feats);

    if (ws_size >= need) {
        short* encb = (short*)((char*)d_ws + off_encb);
        short* whb  = (short*)((char*)d_ws + off_whb);
        float* part = (float*)((char*)d_ws + off_part);
        cvt_bf16_kernel<<<2048, 256, 0, stream>>>(enc, encb, (size_t)B * S * N / 8);
        cvt_bf16_kernel<<<512, 256, 0, stream>>>(Wh, whb, (size_t)N * N / 8);
        score_mfma8_kernel<<<2048, 512, 0, stream>>>(
            encb, whb, bh, dec_feats, cov, wc, v, e);
        softmax_kernel<<<B, 256, 0, stream>>>(e, lens, cov, attn, cov_out);
        context_part_kernel<<<dim3(SCH, B), 256, 0, stream>>>(attn, enc, part);
        context_reduce_kernel<<<(B * N) / 256, 256, 0, stream>>>(part, ctx);
    } else {
        hipMemsetAsync(ctx, 0, (size_t)B * N * sizeof(float), stream);
        score_mfma_kernel<<<(B * S / BR) * (N / BM), 256, 0, stream>>>(
            enc, Wh, bh, dec_feats, cov, wc, v, e);
        softmax_kernel<<<B, 256, 0, stream>>>(e, lens, cov, attn, cov_out);
        context_kernel<<<dim3(SCH, B), 256, 0, stream>>>(attn, enc, ctx);
    }
}

// Round 7
// 1195.497 us; speedup vs baseline: 1.1640x; 1.0314x over previous
//
#include <hip/hip_runtime.h>
#include <math.h>

#define B 32
#define S 4096
#define N 1024

typedef short short8 __attribute__((ext_vector_type(8)));
typedef short short4v __attribute__((ext_vector_type(4)));
typedef float float4v __attribute__((ext_vector_type(4)));

__device__ inline short f2bf(float f) {
    unsigned u = __builtin_bit_cast(unsigned, f);
    u += 0x7fffu + ((u >> 16) & 1u);   // RNE
    return (short)(u >> 16);
}

// async global->LDS DMA, 16 B per lane. LDS dest wave-uniform + lane*16 linear.
__device__ __forceinline__ void load_lds16(const void* g, void* l) {
    __builtin_amdgcn_global_load_lds(
        (const __attribute__((address_space(1))) void*)g,
        (__attribute__((address_space(3))) void*)l, 16, 0, 0);
}

// ---------------------------------------------------------------------------
// Kernel 1: prep = zero(e) + dec_feats, coalesced.
// One wave per (b,m): lanes read 16 consecutive floats each of dec row b and
// Ws row m (fully coalesced), shuffle-reduce the dot. Also zeroes e[B*S].
// ---------------------------------------------------------------------------
__global__ __launch_bounds__(256)
void prep_kernel(const float* __restrict__ dec, const float* __restrict__ Ws,
                 const float* __restrict__ bs, float* __restrict__ dec_feats,
                 float* __restrict__ e) {
    int tg = blockIdx.x * 256 + threadIdx.x;
    if (tg < B * S) e[tg] = 0.f;

    int wid  = (blockIdx.x << 2) + (threadIdx.x >> 6);   // 0..32767 = (m,b)
    int lane = threadIdx.x & 63;
    int m = wid >> 5, b = wid & 31;                      // 4 waves/block share m-locality
    const float4* drow = (const float4*)(dec + (size_t)b * N);
    const float4* wrow = (const float4*)(Ws + (size_t)m * N);
    float acc = 0.f;
#pragma unroll
    for (int k = 0; k < 4; ++k) {
        float4 a = drow[lane + (k << 6)];
        float4 w = wrow[lane + (k << 6)];
        acc += a.x * w.x + a.y * w.y + a.z * w.z + a.w * w.w;
    }
    acc += __shfl_xor(acc, 1);  acc += __shfl_xor(acc, 2);
    acc += __shfl_xor(acc, 4);  acc += __shfl_xor(acc, 8);
    acc += __shfl_xor(acc, 16); acc += __shfl_xor(acc, 32);
    if (lane == 0) dec_feats[(size_t)b * N + m] = acc + bs[m];
}

// ---------------------------------------------------------------------------
// Kernel 1b: fp32 -> bf16 conversion for enc AND Wh in one launch.
// ---------------------------------------------------------------------------
__global__ __launch_bounds__(256)
void cvt_bf16_kernel(const float* __restrict__ enc, short* __restrict__ encb,
                     const float* __restrict__ Wh, short* __restrict__ whb) {
    size_t i0 = (size_t)blockIdx.x * 256 + threadIdx.x;
    size_t stride = (size_t)gridDim.x * 256;
    const size_t n8e = (size_t)B * S * N / 8;
    for (size_t i = i0; i < n8e; i += stride) {
        const float4v* s = (const float4v*)(enc + i * 8);
        float4v a = s[0], b = s[1];
        short8 o = { f2bf(a.x), f2bf(a.y), f2bf(a.z), f2bf(a.w),
                     f2bf(b.x), f2bf(b.y), f2bf(b.z), f2bf(b.w) };
        *(short8*)(encb + i * 8) = o;
    }
    const size_t n8w = (size_t)N * N / 8;
    for (size_t i = i0; i < n8w; i += stride) {
        const float4v* s = (const float4v*)(Wh + i * 8);
        float4v a = s[0], b = s[1];
        short8 o = { f2bf(a.x), f2bf(a.y), f2bf(a.z), f2bf(a.w),
                     f2bf(b.x), f2bf(b.y), f2bf(b.z), f2bf(b.w) };
        *(short8*)(whb + i * 8) = o;
    }
}

// ---------------------------------------------------------------------------
// Kernel 2a: 256x256 8-phase bf16 MFMA GEMM (T1+T2+T3+T4+T5) with fused
// tanh·v epilogue. Schedule verified on-chip r4/r5: 353 µs, MfmaUtil 34,
// SQ_LDS_BANK_CONFLICT 0, absmax 0.0039. DO NOT touch sync structure
// without re-running the r3 FIFO audit. (UNCHANGED.)
// ---------------------------------------------------------------------------
#define REGION_A(slot, hk) ((slot)*16384 + (hk)*8192)
#define REGION_B(slot, hk) (32768 + (slot)*16384 + (hk)*8192)

__global__ __launch_bounds__(512, 2)
void score_mfma8_kernel(const short* __restrict__ encb, const short* __restrict__ whb,
                        const float* __restrict__ bh, const float* __restrict__ dec_feats,
                        const float* __restrict__ cov, const float* __restrict__ wc,
                        const float* __restrict__ v, float* __restrict__ e) {
    __shared__ short lds[65536];   // 128 KiB

    unsigned bid = blockIdx.x;
    unsigned c = (bid & 7u) * 256u + (bid >> 3);
    int rt = (int)(c >> 2), mtile = (int)(c & 3u);
    int r0 = rt * 256, m0 = mtile * 256;

    int t = threadIdx.x, lane = t & 63, w = t >> 6;
    int wm_ = w >> 2, wn_ = w & 3;         // 2 x 4 wave grid
    int cq = lane >> 4, cm = lane & 15;

    int srow = lane >> 2;                              // 0..15 within chunk
    int sg = (lane & 3) ^ ((lane >> 3) & 3);           // logical granule
    const short* aS0 = encb + (size_t)(r0 + w * 16 + srow) * N + sg * 8;
    const short* aS1 = aS0 + (size_t)128 * N;
    const short* bS0 = whb + (size_t)(m0 + w * 16 + srow) * N + sg * 8;
    const short* bS1 = bS0 + (size_t)128 * N;
    const int dc0 = w * 512, dc1 = dc0 + 4096;         // chunk dests (shorts)

    int aoff[8], boff[4];
#pragma unroll
    for (int f = 0; f < 8; ++f) {
        int R = wm_ * 128 + f * 16 + cm;
        aoff[f] = R * 32 + ((cq ^ ((R >> 1) & 3)) << 3);
    }
#pragma unroll
    for (int j = 0; j < 4; ++j) {
        int R = wn_ * 64 + j * 16 + cm;
        boff[j] = R * 32 + ((cq ^ ((R >> 1) & 3)) << 3);
    }

    float4v acc[8][4];
#pragma unroll
    for (int f = 0; f < 8; ++f)
#pragma unroll
        for (int j = 0; j < 4; ++j) acc[f][j] = (float4v){0.f, 0.f, 0.f, 0.f};

#define STAGE(srcp0, srcp1, region, colElem) do {                         \
        int _cc = (colElem) & (N - 1);                                    \
        load_lds16((srcp0) + _cc, &lds[(region) + dc0]);                  \
        load_lds16((srcp1) + _cc, &lds[(region) + dc1]);                  \
    } while (0)

    STAGE(aS0, aS1, REGION_A(0, 0), 0);
    STAGE(bS0, bS1, REGION_B(0, 0), 0);
    STAGE(aS0, aS1, REGION_A(0, 1), 32);
    STAGE(bS0, bS1, REGION_B(0, 1), 32);
    STAGE(aS0, aS1, REGION_A(1, 0), 64);
    STAGE(bS0, bS1, REGION_B(1, 0), 64);
    asm volatile("s_waitcnt vmcnt(8)" ::: "memory");   // loads 1-4 (slot0 h0) done
    __builtin_amdgcn_s_barrier();

    short8 bf[4];

#define PHASE(slot, sub, SRC0, SRC1, SREGION, SCOL) do {                      \
        const int hk_ = (sub) >> 1, mh_ = (sub) & 1;                          \
        if (mh_ == 0) {                                                       \
            _Pragma("unroll")                                                 \
            for (int j = 0; j < 4; ++j)                                       \
                bf[j] = *(const short8*)&lds[REGION_B(slot, hk_) + boff[j]];  \
        }                                                                     \
        short8 af[4];                                                         \
        _Pragma("unroll")                                                     \
        for (int f = 0; f < 4; ++f)                                           \
            af[f] = *(const short8*)&lds[REGION_A(slot, hk_) + aoff[mh_ * 4 + f]]; \
        STAGE(SRC0, SRC1, SREGION, SCOL);                                     \
        __builtin_amdgcn_s_barrier();                                         \
        asm volatile("s_waitcnt lgkmcnt(0)" ::: "memory");                    \
        __builtin_amdgcn_sched_barrier(0);                                    \
        __builtin_amdgcn_s_setprio(1);                                        \
        _Pragma("unroll")                                                     \
        for (int f = 0; f < 4; ++f)                                           \
            _Pragma("unroll")                                                 \
            for (int j = 0; j < 4; ++j)                                       \
                acc[mh_ * 4 + f][j] = __builtin_amdgcn_mfma_f32_16x16x32_bf16(\
                    af[f], bf[j], acc[mh_ * 4 + f][j], 0, 0, 0);              \
        __builtin_amdgcn_s_setprio(0);                                        \
        if (mh_ == 1) asm volatile("s_waitcnt vmcnt(8)" ::: "memory");        \
        __builtin_amdgcn_s_barrier();                                         \
    } while (0)

#pragma unroll 1
    for (int i = 0; i < 8; ++i) {        // 8 iters x 2 K-tiles = K=1024
        int kb = i * 128;
        PHASE(0, 0, aS0, aS1, REGION_A(1, 1), kb + 96);
        PHASE(0, 1, bS0, bS1, REGION_B(1, 1), kb + 96);
        PHASE(0, 2, aS0, aS1, REGION_A(0, 0), kb + 128);
        PHASE(0, 3, bS0, bS1, REGION_B(0, 0), kb + 128);
        PHASE(1, 0, aS0, aS1, REGION_A(0, 1), kb + 160);
        PHASE(1, 1, bS0, bS1, REGION_B(0, 1), kb + 160);
        PHASE(1, 2, aS0, aS1, REGION_A(1, 0), kb + 192);
        PHASE(1, 3, bS0, bS1, REGION_B(1, 0), kb + 192);
    }
    asm volatile("s_waitcnt vmcnt(0)" ::: "memory");
#undef PHASE
#undef STAGE

    // Epilogue. tanh(x) = 1 - 2/(exp2(2*log2e*x)+1).
    int bidx = r0 >> 12;
    const float* df = dec_feats + ((size_t)bidx << 10);

    float basej[4], wcj[4], vj[4];
#pragma unroll
    for (int j = 0; j < 4; ++j) {
        int m = m0 + wn_ * 64 + j * 16 + cm;
        basej[j] = bh[m] + df[m];
        wcj[j]   = wc[m];
        vj[j]    = v[m];
    }

#pragma unroll
    for (int f = 0; f < 8; ++f) {
        int rbase = r0 + wm_ * 128 + f * 16 + cq * 4;
        float4v cvv = *(const float4v*)&cov[rbase];
        float cv[4] = {cvv.x, cvv.y, cvv.z, cvv.w};
        float rs[4] = {0.f, 0.f, 0.f, 0.f};
#pragma unroll
        for (int j = 0; j < 4; ++j) {
#pragma unroll
            for (int reg = 0; reg < 4; ++reg) {
                float val = acc[f][j][reg] + basej[j] + cv[reg] * wcj[j];
                val = fminf(fmaxf(val, -15.f), 15.f);
                float t2 = __builtin_amdgcn_exp2f(val * 2.8853900817779268f);
                float r  = __builtin_amdgcn_rcpf(t2 + 1.f);
                float th = fmaf(-2.f, r, 1.f);
                rs[reg] = fmaf(th, vj[j], rs[reg]);
            }
        }
#pragma unroll
        for (int reg = 0; reg < 4; ++reg) {
            float p = rs[reg];
            p += __shfl_xor(p, 1);
            p += __shfl_xor(p, 2);
            p += __shfl_xor(p, 4);
            p += __shfl_xor(p, 8);
            if (cm == 0) atomicAdd(&e[rbase + reg], p);   // same-XCD only (T1)
        }
    }
}

// ---------------------------------------------------------------------------
// Kernel 2b (fallback if workspace too small): fp32-staging MFMA kernel.
// ---------------------------------------------------------------------------
#define BR 128
#define BM 128
#define BK 64
#define LDK (BK + 8)

__global__ __launch_bounds__(256)
void score_mfma_kernel(const float* __restrict__ enc, const float* __restrict__ Wh,
                       const float* __restrict__ bh, const float* __restrict__ dec_feats,
                       const float* __restrict__ cov, const float* __restrict__ wc,
                       const float* __restrict__ v, float* __restrict__ e) {
    __shared__ short As[BR][LDK];
    __shared__ short Bs[BM][LDK];

    unsigned h   = blockIdx.x;
    unsigned xcd = h & 7u;
    unsigned mt  = (h >> 3) & 7u;
    unsigned g   = h >> 6;
    int r0 = (int)(xcd + 8u * g) * BR;
    int m0 = (int)mt * BM;

    int t    = threadIdx.x;
    int lane = t & 63;
    int w    = t >> 6;
    int wr   = (w >> 1) * 64;
    int wm   = (w & 1) * 64;
    int cq   = lane >> 4;
    int cm   = lane & 15;

    float4v acc[4][4];
#pragma unroll
    for (int i = 0; i < 4; ++i)
#pragma unroll
        for (int j = 0; j < 4; ++j) acc[i][j] = (float4v){0.f, 0.f, 0.f, 0.f};

    int srow = t >> 4;
    int scol = (t & 15) * 4;

    for (int k0 = 0; k0 < N; k0 += BK) {
#pragma unroll
        for (int p = 0; p < 8; ++p) {
            int row = p * 16 + srow;
            float4v a = *(const float4v*)(enc + (size_t)(r0 + row) * N + k0 + scol);
            short4v ap = { f2bf(a.x), f2bf(a.y), f2bf(a.z), f2bf(a.w) };
            *(short4v*)&As[row][scol] = ap;
            float4v bq = *(const float4v*)(Wh + (size_t)(m0 + row) * N + k0 + scol);
            short4v bp = { f2bf(bq.x), f2bf(bq.y), f2bf(bq.z), f2bf(bq.w) };
            *(short4v*)&Bs[row][scol] = bp;
        }
        __syncthreads();
#pragma unroll
        for (int ks = 0; ks < BK; ks += 32) {
            short8 af[4], bfr[4];
#pragma unroll
            for (int i = 0; i < 4; ++i)
                af[i] = *(const short8*)&As[wr + i * 16 + cm][ks + cq * 8];
#pragma unroll
            for (int j = 0; j < 4; ++j)
                bfr[j] = *(const short8*)&Bs[wm + j * 16 + cm][ks + cq * 8];
#pragma unroll
            for (int i = 0; i < 4; ++i)
#pragma unroll
                for (int j = 0; j < 4; ++j)
                    acc[i][j] = __builtin_amdgcn_mfma_f32_16x16x32_bf16(
                        af[i], bfr[j], acc[i][j], 0, 0, 0);
        }
        __syncthreads();
    }

    int b = r0 >> 12;
    const float* df = dec_feats + ((size_t)b << 10);

    float basej[4], wcj[4], vj[4];
#pragma unroll
    for (int j = 0; j < 4; ++j) {
        int m = m0 + wm + j * 16 + cm;
        basej[j] = bh[m] + df[m];
        wcj[j]   = wc[m];
        vj[j]    = v[m];
    }

#pragma unroll
    for (int i = 0; i < 4; ++i) {
        int rbase = r0 + wr + i * 16 + cq * 4;
        float cv[4];
#pragma unroll
        for (int reg = 0; reg < 4; ++reg) cv[reg] = cov[rbase + reg];
        float rs[4] = {0.f, 0.f, 0.f, 0.f};
#pragma unroll
        for (int j = 0; j < 4; ++j) {
#pragma unroll
            for (int reg = 0; reg < 4; ++reg) {
                float val = acc[i][j][reg] + basej[j] + cv[reg] * wcj[j];
                val = fminf(fmaxf(val, -15.f), 15.f);
                float t2 = __builtin_amdgcn_exp2f(val * 2.8853900817779268f);
                float r  = __builtin_amdgcn_rcpf(t2 + 1.f);
                float th = fmaf(-2.f, r, 1.f);
                rs[reg] = fmaf(th, vj[j], rs[reg]);
            }
        }
#pragma unroll
        for (int reg = 0; reg < 4; ++reg) {
            float p = rs[reg];
            p += __shfl_xor(p, 1);
            p += __shfl_xor(p, 2);
            p += __shfl_xor(p, 4);
            p += __shfl_xor(p, 8);
            if (cm == 0) atomicAdd(&e[rbase + reg], p);
        }
    }
}

// ---------------------------------------------------------------------------
// Kernel 3: masked softmax + coverage update. 1024 threads/block, e row held
// in registers (single global read), 2-level shuffle/LDS reductions.
// ---------------------------------------------------------------------------
__global__ __launch_bounds__(1024)
void softmax_kernel(const float* __restrict__ e, const int* __restrict__ lens,
                    const float* __restrict__ cov,
                    float* __restrict__ attn, float* __restrict__ cov_out) {
    int b = blockIdx.x, t = threadIdx.x;
    int lane = t & 63, wid = t >> 6;        // 16 waves
    int len = lens[b];
    const float* eb = e + (size_t)b * S;
    __shared__ float redm[16], reds[16];

    float ev[4];
    float mx = -INFINITY;
#pragma unroll
    for (int k = 0; k < 4; ++k) {
        int s = t + (k << 10);
        ev[k] = (s < len) ? eb[s] : -INFINITY;
        mx = fmaxf(mx, ev[k]);
    }
    mx = fmaxf(mx, __shfl_xor(mx, 1));  mx = fmaxf(mx, __shfl_xor(mx, 2));
    mx = fmaxf(mx, __shfl_xor(mx, 4));  mx = fmaxf(mx, __shfl_xor(mx, 8));
    mx = fmaxf(mx, __shfl_xor(mx, 16)); mx = fmaxf(mx, __shfl_xor(mx, 32));
    if (lane == 0) redm[wid] = mx;
    __syncthreads();
    if (t < 16) {
        float v2 = redm[t];
        v2 = fmaxf(v2, __shfl_xor(v2, 1)); v2 = fmaxf(v2, __shfl_xor(v2, 2));
        v2 = fmaxf(v2, __shfl_xor(v2, 4)); v2 = fmaxf(v2, __shfl_xor(v2, 8));
        if (t == 0) redm[0] = v2;
    }
    __syncthreads();
    mx = redm[0];

    float ex[4];
    float sum = 0.f;
#pragma unroll
    for (int k = 0; k < 4; ++k) {
        ex[k] = exp2f((ev[k] - mx) * 1.4426950408889634f);  // -inf -> 0 for masked
        sum += ex[k];
    }
    sum += __shfl_xor(sum, 1);  sum += __shfl_xor(sum, 2);
    sum += __shfl_xor(sum, 4);  sum += __shfl_xor(sum, 8);
    sum += __shfl_xor(sum, 16); sum += __shfl_xor(sum, 32);
    if (lane == 0) reds[wid] = sum;
    __syncthreads();
    if (t < 16) {
        float v2 = reds[t];
        v2 += __shfl_xor(v2, 1); v2 += __shfl_xor(v2, 2);
        v2 += __shfl_xor(v2, 4); v2 += __shfl_xor(v2, 8);
        if (t == 0) reds[0] = v2;
    }
    __syncthreads();
    float inv = 1.f / reds[0];

#pragma unroll
    for (int k = 0; k < 4; ++k) {
        int s = t + (k << 10);
        float a = ex[k] * inv;
        attn[(size_t)b * S + s] = a;
        cov_out[(size_t)b * S + s] = cov[(size_t)b * S + s] + a;
    }
}

// ---------------------------------------------------------------------------
// Kernel 4: context via two-stage reduction (zero atomics), fp32 enc read
// (bf16 deliberately avoided: absmax sits at 2^-8, don't risk threshold).
// SCH=64 -> 2048 blocks for BW ramp.
// ---------------------------------------------------------------------------
#define SCH 64
__global__ __launch_bounds__(256)
void context_part_kernel(const float* __restrict__ attn, const float* __restrict__ enc,
                         float* __restrict__ part) {
    int b  = blockIdx.y;
    int ch = blockIdx.x;
    int s0 = ch * (S / SCH);
    int n4 = threadIdx.x;
    const float4* ep = (const float4*)(enc + ((size_t)b * S + s0) * N);
    float4 acc = {0.f, 0.f, 0.f, 0.f};
    for (int s = 0; s < S / SCH; ++s) {
        float a = attn[(size_t)b * S + s0 + s];
        float4 ev = ep[(size_t)s * (N / 4) + n4];
        acc.x += a * ev.x; acc.y += a * ev.y;
        acc.z += a * ev.z; acc.w += a * ev.w;
    }
    *(float4*)&part[((size_t)b * SCH + ch) * N + n4 * 4] = acc;
}

__global__ __launch_bounds__(256)
void context_reduce_kernel(const float* __restrict__ part, float* __restrict__ ctx) {
    int idx = blockIdx.x * 256 + threadIdx.x;   // 0 .. B*N-1
    int b = idx >> 10, n = idx & (N - 1);
    const float* p = part + (size_t)b * SCH * N + n;
    float acc = 0.f;
#pragma unroll
    for (int c2 = 0; c2 < SCH; ++c2) acc += p[(size_t)c2 * N];
    ctx[idx] = acc;
}

// ---------------------------------------------------------------------------
// Kernel 4b (fallback): atomic context kernel (needs ctx pre-zeroed).
// ---------------------------------------------------------------------------
__global__ __launch_bounds__(256)
void context_kernel(const float* __restrict__ attn, const float* __restrict__ enc,
                    float* __restrict__ ctx) {
    int b  = blockIdx.y;
    int s0 = blockIdx.x * (S / SCH);
    int n4 = threadIdx.x;
    const float4* ep = (const float4*)(enc + ((size_t)b * S + s0) * N);
    float4 acc = {0.f, 0.f, 0.f, 0.f};
    for (int s = 0; s < S / SCH; ++s) {
        float a = attn[(size_t)b * S + s0 + s];
        float4 ev = ep[(size_t)s * (N / 4) + n4];
        acc.x += a * ev.x; acc.y += a * ev.y;
        acc.z += a * ev.z; acc.w += a * ev.w;
    }
    float* cp = ctx + (size_t)b * N + n4 * 4;
    atomicAdd(cp + 0, acc.x);
    atomicAdd(cp + 1, acc.y);
    atomicAdd(cp + 2, acc.z);
    atomicAdd(cp + 3, acc.w);
}

// ---------------------------------------------------------------------------
extern "C" void kernel_launch(void* const* d_in, const int* in_sizes, int n_in,
                              void* d_out, int out_size, void* d_ws, size_t ws_size,
                              hipStream_t stream) {
    const float* dec  = (const float*)d_in[0];
    const float* enc  = (const float*)d_in[1];
    const int*   lens = (const int*)  d_in[2];
    const float* cov  = (const float*)d_in[3];
    const float* Wh   = (const float*)d_in[4];
    const float* bh   = (const float*)d_in[5];
    const float* Ws   = (const float*)d_in[6];
    const float* bs   = (const float*)d_in[7];
    const float* wc   = (const float*)d_in[8];
    const float* v    = (const float*)d_in[9];

    float* out     = (float*)d_out;
    float* ctx     = out;                    // B*N
    float* attn    = out + (size_t)B * N;    // B*S
    float* cov_out = attn + (size_t)B * S;   // B*S

    size_t off_e    = (size_t)B * N * 4;
    size_t off_encb = off_e + (size_t)B * S * 4;
    size_t off_whb  = off_encb + (size_t)B * S * N * 2;
    size_t off_part = off_whb + (size_t)N * N * 2;
    size_t need     = off_part + (size_t)B * SCH * N * 4;

    float* dec_feats = (float*)d_ws;
    float* e         = (float*)((char*)d_ws + off_e);

    // prep: zero(e) + dec_feats (replaces memset + old dec_feats kernel)
    prep_kernel<<<8192, 256, 0, stream>>>(dec, Ws, bs, dec_feats, e);

    if (ws_size >= need) {
        short* encb = (short*)((char*)d_ws + off_encb);
        short* whb  = (short*)((char*)d_ws + off_whb);
        float* part = (float*)((char*)d_ws + off_part);
        cvt_bf16_kernel<<<2048, 256, 0, stream>>>(enc, encb, Wh, whb);
        score_mfma8_kernel<<<2048, 512, 0, stream>>>(
            encb, whb, bh, dec_feats, cov, wc, v, e);
        softmax_kernel<<<B, 1024, 0, stream>>>(e, lens, cov, attn, cov_out);
        context_part_kernel<<<dim3(SCH, B), 256, 0, stream>>>(attn, enc, part);
        context_reduce_kernel<<<(B * N) / 256, 256, 0, stream>>>(part, ctx);
    } else {
        hipMemsetAsync(ctx, 0, (size_t)B * N * sizeof(float), stream);
        score_mfma_kernel<<<(B * S / BR) * (N / BM), 256, 0, stream>>>(
            enc, Wh, bh, dec_feats, cov, wc, v, e);
        softmax_kernel<<<B, 1024, 0, stream>>>(e, lens, cov, attn, cov_out);
        context_kernel<<<dim3(SCH, B), 256, 0, stream>>>(attn, enc, ctx);
    }
}

// Round 8
// 1156.325 us; speedup vs baseline: 1.2034x; 1.0339x over previous
//
#include <hip/hip_runtime.h>
#include <math.h>

#define B 32
#define S 4096
#define N 1024

typedef short short8 __attribute__((ext_vector_type(8)));
typedef short short4v __attribute__((ext_vector_type(4)));
typedef float float4v __attribute__((ext_vector_type(4)));

__device__ inline short f2bf(float f) {
    unsigned u = __builtin_bit_cast(unsigned, f);
    u += 0x7fffu + ((u >> 16) & 1u);   // RNE
    return (short)(u >> 16);
}

// async global->LDS DMA, 16 B per lane. LDS dest wave-uniform + lane*16 linear.
__device__ __forceinline__ void load_lds16(const void* g, void* l) {
    __builtin_amdgcn_global_load_lds(
        (const __attribute__((address_space(1))) void*)g,
        (__attribute__((address_space(3))) void*)l, 16, 0, 0);
}

// ---------------------------------------------------------------------------
// Kernel 1 (fast path): fused front-end.
//   blocks [0,2048):    cvt enc fp32->bf16 (grid-stride); blocks [0,512) also
//                       zero e[B*S].
//   blocks [2048,2064):  cvt Wh fp32->bf16.
//   blocks [2064,10256): dec_feats, one wave per (b,m), coalesced + shuffle.
// L2-bound dec_feats waves overlap HBM-bound cvt blocks.
// ---------------------------------------------------------------------------
__global__ __launch_bounds__(256)
void prep_cvt_kernel(const float* __restrict__ dec, const float* __restrict__ Ws,
                     const float* __restrict__ bs, const float* __restrict__ enc,
                     const float* __restrict__ Wh, float* __restrict__ dec_feats,
                     float* __restrict__ e, short* __restrict__ encb,
                     short* __restrict__ whb) {
    unsigned bid = blockIdx.x;
    int tid = threadIdx.x;
    if (bid < 2048u) {
        if (bid < 512u) e[bid * 256 + tid] = 0.f;
        const size_t n8e = (size_t)B * S * N / 8;
        for (size_t i = (size_t)bid * 256 + tid; i < n8e; i += 2048u * 256u) {
            const float4v* s = (const float4v*)(enc + i * 8);
            float4v a = s[0], b = s[1];
            short8 o = { f2bf(a.x), f2bf(a.y), f2bf(a.z), f2bf(a.w),
                         f2bf(b.x), f2bf(b.y), f2bf(b.z), f2bf(b.w) };
            *(short8*)(encb + i * 8) = o;
        }
    } else if (bid < 2064u) {
        const size_t n8w = (size_t)N * N / 8;
        for (size_t i = (size_t)(bid - 2048u) * 256 + tid; i < n8w; i += 16u * 256u) {
            const float4v* s = (const float4v*)(Wh + i * 8);
            float4v a = s[0], b = s[1];
            short8 o = { f2bf(a.x), f2bf(a.y), f2bf(a.z), f2bf(a.w),
                         f2bf(b.x), f2bf(b.y), f2bf(b.z), f2bf(b.w) };
            *(short8*)(whb + i * 8) = o;
        }
    } else {
        int wid  = (int)(bid - 2064u) * 4 + (tid >> 6);  // 0..32767 = (m,b)
        int lane = tid & 63;
        int m = wid >> 5, b = wid & 31;
        const float4* drow = (const float4*)(dec + (size_t)b * N);
        const float4* wrow = (const float4*)(Ws + (size_t)m * N);
        float acc = 0.f;
#pragma unroll
        for (int k = 0; k < 4; ++k) {
            float4 a = drow[lane + (k << 6)];
            float4 w = wrow[lane + (k << 6)];
            acc += a.x * w.x + a.y * w.y + a.z * w.z + a.w * w.w;
        }
        acc += __shfl_xor(acc, 1);  acc += __shfl_xor(acc, 2);
        acc += __shfl_xor(acc, 4);  acc += __shfl_xor(acc, 8);
        acc += __shfl_xor(acc, 16); acc += __shfl_xor(acc, 32);
        if (lane == 0) dec_feats[(size_t)b * N + m] = acc + bs[m];
    }
}

// ---------------------------------------------------------------------------
// Kernel 1b (fallback path): zero(e) + dec_feats only.
// ---------------------------------------------------------------------------
__global__ __launch_bounds__(256)
void prep_kernel(const float* __restrict__ dec, const float* __restrict__ Ws,
                 const float* __restrict__ bs, float* __restrict__ dec_feats,
                 float* __restrict__ e) {
    int tg = blockIdx.x * 256 + threadIdx.x;
    if (tg < B * S) e[tg] = 0.f;
    int wid  = (blockIdx.x << 2) + (threadIdx.x >> 6);
    int lane = threadIdx.x & 63;
    int m = wid >> 5, b = wid & 31;
    const float4* drow = (const float4*)(dec + (size_t)b * N);
    const float4* wrow = (const float4*)(Ws + (size_t)m * N);
    float acc = 0.f;
#pragma unroll
    for (int k = 0; k < 4; ++k) {
        float4 a = drow[lane + (k << 6)];
        float4 w = wrow[lane + (k << 6)];
        acc += a.x * w.x + a.y * w.y + a.z * w.z + a.w * w.w;
    }
    acc += __shfl_xor(acc, 1);  acc += __shfl_xor(acc, 2);
    acc += __shfl_xor(acc, 4);  acc += __shfl_xor(acc, 8);
    acc += __shfl_xor(acc, 16); acc += __shfl_xor(acc, 32);
    if (lane == 0) dec_feats[(size_t)b * N + m] = acc + bs[m];
}

// ---------------------------------------------------------------------------
// Kernel 2a: 256x256 8-phase bf16 MFMA GEMM (T1+T2+T3+T4+T5), fused tanh·v
// epilogue. Inner schedule chip-verified (r4/r5/r7: MfmaUtil 34, conflicts 0,
// absmax 0.0039) — UNCHANGED. New in r7: each block processes TWO consecutive
// row-tiles (fixed m-tile) to amortize prologue/epilogue and reuse B panels.
// Seam audit: epilogue atomics increment vmcnt -> drain vmcnt(0) + barrier
// before next tile's prologue (else prologue's vmcnt(8) releases early).
// LDS clean across seam: last phase's lgkmcnt(0) precedes its closing barrier;
// epilogue touches no LDS.
// ---------------------------------------------------------------------------
#define REGION_A(slot, hk) ((slot)*16384 + (hk)*8192)
#define REGION_B(slot, hk) (32768 + (slot)*16384 + (hk)*8192)

__global__ __launch_bounds__(512, 2)
void score_mfma8_kernel(const short* __restrict__ encb, const short* __restrict__ whb,
                        const float* __restrict__ bh, const float* __restrict__ dec_feats,
                        const float* __restrict__ cov, const float* __restrict__ wc,
                        const float* __restrict__ v, float* __restrict__ e) {
    __shared__ short lds[65536];   // 128 KiB

    // T1: bijective XCD swizzle (1024 % 8 == 0). Each block: fixed m-tile,
    // row-tiles 2*rtp and 2*rtp+1 (always same batch: pairs never straddle
    // the 16-tile batch boundary).
    unsigned bid = blockIdx.x;
    unsigned c = (bid & 7u) * 128u + (bid >> 3);
    int rtp = (int)(c >> 2), mtile = (int)(c & 3u);
    int m0 = mtile * 256;

    int t = threadIdx.x, lane = t & 63, w = t >> 6;
    int wm_ = w >> 2, wn_ = w & 3;         // 2 x 4 wave grid
    int cq = lane >> 4, cm = lane & 15;

    int srow = lane >> 2;                              // 0..15 within chunk
    int sg = (lane & 3) ^ ((lane >> 3) & 3);           // logical granule
    const short* bS0 = whb + (size_t)(m0 + w * 16 + srow) * N + sg * 8;
    const short* bS1 = bS0 + (size_t)128 * N;
    const int dc0 = w * 512, dc1 = dc0 + 4096;         // chunk dests (shorts)

    int aoff[8], boff[4];
#pragma unroll
    for (int f = 0; f < 8; ++f) {
        int R = wm_ * 128 + f * 16 + cm;
        aoff[f] = R * 32 + ((cq ^ ((R >> 1) & 3)) << 3);
    }
#pragma unroll
    for (int j = 0; j < 4; ++j) {
        int R = wn_ * 64 + j * 16 + cm;
        boff[j] = R * 32 + ((cq ^ ((R >> 1) & 3)) << 3);
    }

    float basej[4], wcj[4], vj[4];   // m-side constants: invariant across tiles
    {
        int bidx0 = (rtp * 2 * 256) >> 12;
        const float* df = dec_feats + ((size_t)bidx0 << 10);
#pragma unroll
        for (int j = 0; j < 4; ++j) {
            int m = m0 + wn_ * 64 + j * 16 + cm;
            basej[j] = bh[m] + df[m];
            wcj[j]   = wc[m];
            vj[j]    = v[m];
        }
    }

#define STAGE(srcp0, srcp1, region, colElem) do {                         \
        int _cc = (colElem) & (N - 1);                                    \
        load_lds16((srcp0) + _cc, &lds[(region) + dc0]);                  \
        load_lds16((srcp1) + _cc, &lds[(region) + dc1]);                  \
    } while (0)

#define PHASE(slot, sub, SRC0, SRC1, SREGION, SCOL) do {                      \
        const int hk_ = (sub) >> 1, mh_ = (sub) & 1;                          \
        if (mh_ == 0) {                                                       \
            _Pragma("unroll")                                                 \
            for (int j = 0; j < 4; ++j)                                       \
                bf[j] = *(const short8*)&lds[REGION_B(slot, hk_) + boff[j]];  \
        }                                                                     \
        short8 af[4];                                                         \
        _Pragma("unroll")                                                     \
        for (int f = 0; f < 4; ++f)                                           \
            af[f] = *(const short8*)&lds[REGION_A(slot, hk_) + aoff[mh_ * 4 + f]]; \
        STAGE(SRC0, SRC1, SREGION, SCOL);                                     \
        __builtin_amdgcn_s_barrier();                                         \
        asm volatile("s_waitcnt lgkmcnt(0)" ::: "memory");                    \
        __builtin_amdgcn_sched_barrier(0);                                    \
        __builtin_amdgcn_s_setprio(1);                                        \
        _Pragma("unroll")                                                     \
        for (int f = 0; f < 4; ++f)                                           \
            _Pragma("unroll")                                                 \
            for (int j = 0; j < 4; ++j)                                       \
                acc[mh_ * 4 + f][j] = __builtin_amdgcn_mfma_f32_16x16x32_bf16(\
                    af[f], bf[j], acc[mh_ * 4 + f][j], 0, 0, 0);              \
        __builtin_amdgcn_s_setprio(0);                                        \
        if (mh_ == 1) asm volatile("s_waitcnt vmcnt(8)" ::: "memory");        \
        __builtin_amdgcn_s_barrier();                                         \
    } while (0)

#pragma unroll 1
    for (int it = 0; it < 2; ++it) {
        int r0 = (rtp * 2 + it) * 256;
        const short* aS0 = encb + (size_t)(r0 + w * 16 + srow) * N + sg * 8;
        const short* aS1 = aS0 + (size_t)128 * N;

        float4v acc[8][4];
#pragma unroll
        for (int f = 0; f < 8; ++f)
#pragma unroll
            for (int j = 0; j < 4; ++j) acc[f][j] = (float4v){0.f, 0.f, 0.f, 0.f};

        // Prologue: kt0 (slot0 both halves) + kt1 half0 (slot1). 12 loads.
        STAGE(aS0, aS1, REGION_A(0, 0), 0);
        STAGE(bS0, bS1, REGION_B(0, 0), 0);
        STAGE(aS0, aS1, REGION_A(0, 1), 32);
        STAGE(bS0, bS1, REGION_B(0, 1), 32);
        STAGE(aS0, aS1, REGION_A(1, 0), 64);
        STAGE(bS0, bS1, REGION_B(1, 0), 64);
        asm volatile("s_waitcnt vmcnt(8)" ::: "memory");   // slot0 h0 done
        __builtin_amdgcn_s_barrier();

        short8 bf[4];

#pragma unroll 1
        for (int i = 0; i < 8; ++i) {        // 8 iters x 2 K-tiles = K=1024
            int kb = i * 128;
            PHASE(0, 0, aS0, aS1, REGION_A(1, 1), kb + 96);
            PHASE(0, 1, bS0, bS1, REGION_B(1, 1), kb + 96);
            PHASE(0, 2, aS0, aS1, REGION_A(0, 0), kb + 128);
            PHASE(0, 3, bS0, bS1, REGION_B(0, 0), kb + 128);
            PHASE(1, 0, aS0, aS1, REGION_A(0, 1), kb + 160);
            PHASE(1, 1, bS0, bS1, REGION_B(0, 1), kb + 160);
            PHASE(1, 2, aS0, aS1, REGION_A(1, 0), kb + 192);
            PHASE(1, 3, bS0, bS1, REGION_B(1, 0), kb + 192);
        }
        asm volatile("s_waitcnt vmcnt(0)" ::: "memory");

        // Epilogue. tanh(x) = 1 - 2/(exp2(2*log2e*x)+1).
#pragma unroll
        for (int f = 0; f < 8; ++f) {
            int rbase = r0 + wm_ * 128 + f * 16 + cq * 4;
            float4v cvv = *(const float4v*)&cov[rbase];
            float cv[4] = {cvv.x, cvv.y, cvv.z, cvv.w};
            float rs[4] = {0.f, 0.f, 0.f, 0.f};
#pragma unroll
            for (int j = 0; j < 4; ++j) {
#pragma unroll
                for (int reg = 0; reg < 4; ++reg) {
                    float val = acc[f][j][reg] + basej[j] + cv[reg] * wcj[j];
                    val = fminf(fmaxf(val, -15.f), 15.f);
                    float t2 = __builtin_amdgcn_exp2f(val * 2.8853900817779268f);
                    float r  = __builtin_amdgcn_rcpf(t2 + 1.f);
                    float th = fmaf(-2.f, r, 1.f);
                    rs[reg] = fmaf(th, vj[j], rs[reg]);
                }
            }
#pragma unroll
            for (int reg = 0; reg < 4; ++reg) {
                float p = rs[reg];
                p += __shfl_xor(p, 1);
                p += __shfl_xor(p, 2);
                p += __shfl_xor(p, 4);
                p += __shfl_xor(p, 8);
                if (cm == 0) atomicAdd(&e[rbase + reg], p);   // same-XCD (T1)
            }
        }
        // Seam: drain epilogue atomics from vmcnt so next prologue's
        // vmcnt(8) counts only its own 12 loads; align waves.
        asm volatile("s_waitcnt vmcnt(0)" ::: "memory");
        __builtin_amdgcn_s_barrier();
    }
#undef PHASE
#undef STAGE
}

// ---------------------------------------------------------------------------
// Kernel 2b (fallback if workspace too small): fp32-staging MFMA kernel.
// ---------------------------------------------------------------------------
#define BR 128
#define BM 128
#define BK 64
#define LDK (BK + 8)

__global__ __launch_bounds__(256)
void score_mfma_kernel(const float* __restrict__ enc, const float* __restrict__ Wh,
                       const float* __restrict__ bh, const float* __restrict__ dec_feats,
                       const float* __restrict__ cov, const float* __restrict__ wc,
                       const float* __restrict__ v, float* __restrict__ e) {
    __shared__ short As[BR][LDK];
    __shared__ short Bs[BM][LDK];

    unsigned h   = blockIdx.x;
    unsigned xcd = h & 7u;
    unsigned mt  = (h >> 3) & 7u;
    unsigned g   = h >> 6;
    int r0 = (int)(xcd + 8u * g) * BR;
    int m0 = (int)mt * BM;

    int t    = threadIdx.x;
    int lane = t & 63;
    int w    = t >> 6;
    int wr   = (w >> 1) * 64;
    int wm   = (w & 1) * 64;
    int cq   = lane >> 4;
    int cm   = lane & 15;

    float4v acc[4][4];
#pragma unroll
    for (int i = 0; i < 4; ++i)
#pragma unroll
        for (int j = 0; j < 4; ++j) acc[i][j] = (float4v){0.f, 0.f, 0.f, 0.f};

    int srow = t >> 4;
    int scol = (t & 15) * 4;

    for (int k0 = 0; k0 < N; k0 += BK) {
#pragma unroll
        for (int p = 0; p < 8; ++p) {
            int row = p * 16 + srow;
            float4v a = *(const float4v*)(enc + (size_t)(r0 + row) * N + k0 + scol);
            short4v ap = { f2bf(a.x), f2bf(a.y), f2bf(a.z), f2bf(a.w) };
            *(short4v*)&As[row][scol] = ap;
            float4v bq = *(const float4v*)(Wh + (size_t)(m0 + row) * N + k0 + scol);
            short4v bp = { f2bf(bq.x), f2bf(bq.y), f2bf(bq.z), f2bf(bq.w) };
            *(short4v*)&Bs[row][scol] = bp;
        }
        __syncthreads();
#pragma unroll
        for (int ks = 0; ks < BK; ks += 32) {
            short8 af[4], bfr[4];
#pragma unroll
            for (int i = 0; i < 4; ++i)
                af[i] = *(const short8*)&As[wr + i * 16 + cm][ks + cq * 8];
#pragma unroll
            for (int j = 0; j < 4; ++j)
                bfr[j] = *(const short8*)&Bs[wm + j * 16 + cm][ks + cq * 8];
#pragma unroll
            for (int i = 0; i < 4; ++i)
#pragma unroll
                for (int j = 0; j < 4; ++j)
                    acc[i][j] = __builtin_amdgcn_mfma_f32_16x16x32_bf16(
                        af[i], bfr[j], acc[i][j], 0, 0, 0);
        }
        __syncthreads();
    }

    int b = r0 >> 12;
    const float* df = dec_feats + ((size_t)b << 10);

    float basej[4], wcj[4], vj[4];
#pragma unroll
    for (int j = 0; j < 4; ++j) {
        int m = m0 + wm + j * 16 + cm;
        basej[j] = bh[m] + df[m];
        wcj[j]   = wc[m];
        vj[j]    = v[m];
    }

#pragma unroll
    for (int i = 0; i < 4; ++i) {
        int rbase = r0 + wr + i * 16 + cq * 4;
        float cv[4];
#pragma unroll
        for (int reg = 0; reg < 4; ++reg) cv[reg] = cov[rbase + reg];
        float rs[4] = {0.f, 0.f, 0.f, 0.f};
#pragma unroll
        for (int j = 0; j < 4; ++j) {
#pragma unroll
            for (int reg = 0; reg < 4; ++reg) {
                float val = acc[i][j][reg] + basej[j] + cv[reg] * wcj[j];
                val = fminf(fmaxf(val, -15.f), 15.f);
                float t2 = __builtin_amdgcn_exp2f(val * 2.8853900817779268f);
                float r  = __builtin_amdgcn_rcpf(t2 + 1.f);
                float th = fmaf(-2.f, r, 1.f);
                rs[reg] = fmaf(th, vj[j], rs[reg]);
            }
        }
#pragma unroll
        for (int reg = 0; reg < 4; ++reg) {
            float p = rs[reg];
            p += __shfl_xor(p, 1);
            p += __shfl_xor(p, 2);
            p += __shfl_xor(p, 4);
            p += __shfl_xor(p, 8);
            if (cm == 0) atomicAdd(&e[rbase + reg], p);
        }
    }
}

// ---------------------------------------------------------------------------
// Kernel 3: masked softmax + coverage update. 1024 threads/block, e in regs.
// ---------------------------------------------------------------------------
__global__ __launch_bounds__(1024)
void softmax_kernel(const float* __restrict__ e, const int* __restrict__ lens,
                    const float* __restrict__ cov,
                    float* __restrict__ attn, float* __restrict__ cov_out) {
    int b = blockIdx.x, t = threadIdx.x;
    int lane = t & 63, wid = t >> 6;        // 16 waves
    int len = lens[b];
    const float* eb = e + (size_t)b * S;
    __shared__ float redm[16], reds[16];

    float ev[4];
    float mx = -INFINITY;
#pragma unroll
    for (int k = 0; k < 4; ++k) {
        int s = t + (k << 10);
        ev[k] = (s < len) ? eb[s] : -INFINITY;
        mx = fmaxf(mx, ev[k]);
    }
    mx = fmaxf(mx, __shfl_xor(mx, 1));  mx = fmaxf(mx, __shfl_xor(mx, 2));
    mx = fmaxf(mx, __shfl_xor(mx, 4));  mx = fmaxf(mx, __shfl_xor(mx, 8));
    mx = fmaxf(mx, __shfl_xor(mx, 16)); mx = fmaxf(mx, __shfl_xor(mx, 32));
    if (lane == 0) redm[wid] = mx;
    __syncthreads();
    if (t < 16) {
        float v2 = redm[t];
        v2 = fmaxf(v2, __shfl_xor(v2, 1)); v2 = fmaxf(v2, __shfl_xor(v2, 2));
        v2 = fmaxf(v2, __shfl_xor(v2, 4)); v2 = fmaxf(v2, __shfl_xor(v2, 8));
        if (t == 0) redm[0] = v2;
    }
    __syncthreads();
    mx = redm[0];

    float ex[4];
    float sum = 0.f;
#pragma unroll
    for (int k = 0; k < 4; ++k) {
        ex[k] = exp2f((ev[k] - mx) * 1.4426950408889634f);
        sum += ex[k];
    }
    sum += __shfl_xor(sum, 1);  sum += __shfl_xor(sum, 2);
    sum += __shfl_xor(sum, 4);  sum += __shfl_xor(sum, 8);
    sum += __shfl_xor(sum, 16); sum += __shfl_xor(sum, 32);
    if (lane == 0) reds[wid] = sum;
    __syncthreads();
    if (t < 16) {
        float v2 = reds[t];
        v2 += __shfl_xor(v2, 1); v2 += __shfl_xor(v2, 2);
        v2 += __shfl_xor(v2, 4); v2 += __shfl_xor(v2, 8);
        if (t == 0) reds[0] = v2;
    }
    __syncthreads();
    float inv = 1.f / reds[0];

#pragma unroll
    for (int k = 0; k < 4; ++k) {
        int s = t + (k << 10);
        float a = ex[k] * inv;
        attn[(size_t)b * S + s] = a;
        cov_out[(size_t)b * S + s] = cov[(size_t)b * S + s] + a;
    }
}

// ---------------------------------------------------------------------------
// Kernel 4: context via two-stage reduction (zero atomics), fp32 enc read.
// ---------------------------------------------------------------------------
#define SCH 64
__global__ __launch_bounds__(256)
void context_part_kernel(const float* __restrict__ attn, const float* __restrict__ enc,
                         float* __restrict__ part) {
    int b  = blockIdx.y;
    int ch = blockIdx.x;
    int s0 = ch * (S / SCH);
    int n4 = threadIdx.x;
    const float4* ep = (const float4*)(enc + ((size_t)b * S + s0) * N);
    float4 acc = {0.f, 0.f, 0.f, 0.f};
    for (int s = 0; s < S / SCH; ++s) {
        float a = attn[(size_t)b * S + s0 + s];
        float4 ev = ep[(size_t)s * (N / 4) + n4];
        acc.x += a * ev.x; acc.y += a * ev.y;
        acc.z += a * ev.z; acc.w += a * ev.w;
    }
    *(float4*)&part[((size_t)b * SCH + ch) * N + n4 * 4] = acc;
}

__global__ __launch_bounds__(256)
void context_reduce_kernel(const float* __restrict__ part, float* __restrict__ ctx) {
    int idx = blockIdx.x * 256 + threadIdx.x;   // 0 .. B*N-1
    int b = idx >> 10, n = idx & (N - 1);
    const float* p = part + (size_t)b * SCH * N + n;
    float acc = 0.f;
#pragma unroll
    for (int c2 = 0; c2 < SCH; ++c2) acc += p[(size_t)c2 * N];
    ctx[idx] = acc;
}

// ---------------------------------------------------------------------------
// Kernel 4b (fallback): atomic context kernel (needs ctx pre-zeroed).
// ---------------------------------------------------------------------------
__global__ __launch_bounds__(256)
void context_kernel(const float* __restrict__ attn, const float* __restrict__ enc,
                    float* __restrict__ ctx) {
    int b  = blockIdx.y;
    int s0 = blockIdx.x * (S / SCH);
    int n4 = threadIdx.x;
    const float4* ep = (const float4*)(enc + ((size_t)b * S + s0) * N);
    float4 acc = {0.f, 0.f, 0.f, 0.f};
    for (int s = 0; s < S / SCH; ++s) {
        float a = attn[(size_t)b * S + s0 + s];
        float4 ev = ep[(size_t)s * (N / 4) + n4];
        acc.x += a * ev.x; acc.y += a * ev.y;
        acc.z += a * ev.z; acc.w += a * ev.w;
    }
    float* cp = ctx + (size_t)b * N + n4 * 4;
    atomicAdd(cp + 0, acc.x);
    atomicAdd(cp + 1, acc.y);
    atomicAdd(cp + 2, acc.z);
    atomicAdd(cp + 3, acc.w);
}

// ---------------------------------------------------------------------------
extern "C" void kernel_launch(void* const* d_in, const int* in_sizes, int n_in,
                              void* d_out, int out_size, void* d_ws, size_t ws_size,
                              hipStream_t stream) {
    const float* dec  = (const float*)d_in[0];
    const float* enc  = (const float*)d_in[1];
    const int*   lens = (const int*)  d_in[2];
    const float* cov  = (const float*)d_in[3];
    const float* Wh   = (const float*)d_in[4];
    const float* bh   = (const float*)d_in[5];
    const float* Ws   = (const float*)d_in[6];
    const float* bs   = (const float*)d_in[7];
    const float* wc   = (const float*)d_in[8];
    const float* v    = (const float*)d_in[9];

    float* out     = (float*)d_out;
    float* ctx     = out;                    // B*N
    float* attn    = out + (size_t)B * N;    // B*S
    float* cov_out = attn + (size_t)B * S;   // B*S

    size_t off_e    = (size_t)B * N * 4;
    size_t off_encb = off_e + (size_t)B * S * 4;
    size_t off_whb  = off_encb + (size_t)B * S * N * 2;
    size_t off_part = off_whb + (size_t)N * N * 2;
    size_t need     = off_part + (size_t)B * SCH * N * 4;

    float* dec_feats = (float*)d_ws;
    float* e         = (float*)((char*)d_ws + off_e);

    if (ws_size >= need) {
        short* encb = (short*)((char*)d_ws + off_encb);
        short* whb  = (short*)((char*)d_ws + off_whb);
        float* part = (float*)((char*)d_ws + off_part);
        prep_cvt_kernel<<<10256, 256, 0, stream>>>(dec, Ws, bs, enc, Wh,
                                                   dec_feats, e, encb, whb);
        score_mfma8_kernel<<<1024, 512, 0, stream>>>(
            encb, whb, bh, dec_feats, cov, wc, v, e);
        softmax_kernel<<<B, 1024, 0, stream>>>(e, lens, cov, attn, cov_out);
        context_part_kernel<<<dim3(SCH, B), 256, 0, stream>>>(attn, enc, part);
        context_reduce_kernel<<<(B * N) / 256, 256, 0, stream>>>(part, ctx);
    } else {
        prep_kernel<<<8192, 256, 0, stream>>>(dec, Ws, bs, dec_feats, e);
        hipMemsetAsync(ctx, 0, (size_t)B * N * sizeof(float), stream);
        score_mfma_kernel<<<(B * S / BR) * (N / BM), 256, 0, stream>>>(
            enc, Wh, bh, dec_feats, cov, wc, v, e);
        softmax_kernel<<<B, 1024, 0, stream>>>(e, lens, cov, attn, cov_out);
        context_kernel<<<dim3(SCH, B), 256, 0, stream>>>(attn, enc, ctx);
    }
}